// Round 2
// baseline (2002.683 us; speedup 1.0000x reference)
//
#include <hip/hip_runtime.h>
#include <math.h>

#define D_MODEL 1024
#define D_INNER 2048
#define D_STATE 16
#define D_CONV  4

__device__ __forceinline__ float silu_f(float x) { return x / (1.f + __expf(-x)); }
__device__ __forceinline__ float softplus_f(float x) {
    return fmaxf(x, 0.f) + log1pf(__expf(-fabsf(x)));
}

// ---------------------------------------------------------------------------
// Generic tiled fp32 GEMM: C = A(MxK) * B(KxN) + bias, with fused epilogues.
// MODE 0: split columns: c<D_INNER -> out0 = silu(v); else out1 = v   (in_proj)
// MODE 1: out0 = softplus(v)                                          (dt_proj)
// MODE 2: out0 = v + aux[row*N+c]                                     (out_proj+residual)
// Tile: 64x64, BK=16, 256 threads, 4x4 micro-tile per thread.
// ---------------------------------------------------------------------------
template <int MODE>
__global__ __launch_bounds__(256)
void gemm_tiled(const float* __restrict__ A, const float* __restrict__ B,
                const float* __restrict__ bias, const float* __restrict__ aux,
                float* __restrict__ out0, float* __restrict__ out1,
                int M, int N, int K)
{
    const int bx = blockIdx.x, by = blockIdx.y;
    const int tid = threadIdx.x;
    const int tx = tid & 15, ty = tid >> 4;

    __shared__ float As[16][68];   // transposed A tile: As[k][m], padded
    __shared__ float Bs[16][64];   // Bs[k][n]

    float acc[4][4] = {};

    const int row0 = by * 64, col0 = bx * 64;
    const int am = tid >> 2, ak = (tid & 3) << 2;   // A tile load: row m, k-offset
    const int bk = tid >> 4, bn = (tid & 15) << 2;  // B tile load: k row, n-offset

    for (int k0 = 0; k0 < K; k0 += 16) {
        float4 av = *(const float4*)&A[(size_t)(row0 + am) * K + k0 + ak];
        float4 bv = *(const float4*)&B[(size_t)(k0 + bk) * N + col0 + bn];
        __syncthreads();  // previous iteration's reads done before overwrite
        As[ak + 0][am] = av.x;
        As[ak + 1][am] = av.y;
        As[ak + 2][am] = av.z;
        As[ak + 3][am] = av.w;
        *(float4*)&Bs[bk][bn] = bv;
        __syncthreads();
#pragma unroll
        for (int k = 0; k < 16; k++) {
            const float4 a = *(const float4*)&As[k][ty << 2];
            const float4 b = *(const float4*)&Bs[k][tx << 2];
            const float af[4] = {a.x, a.y, a.z, a.w};
            const float bf[4] = {b.x, b.y, b.z, b.w};
#pragma unroll
            for (int i = 0; i < 4; i++)
#pragma unroll
                for (int j = 0; j < 4; j++)
                    acc[i][j] = fmaf(af[i], bf[j], acc[i][j]);
        }
    }

#pragma unroll
    for (int i = 0; i < 4; i++) {
        const int r = row0 + (ty << 2) + i;
#pragma unroll
        for (int j = 0; j < 4; j++) {
            const int c = col0 + (tx << 2) + j;
            float v = acc[i][j] + bias[c];
            if (MODE == 0) {
                if (c < D_INNER) out0[(size_t)r * D_INNER + c] = silu_f(v);
                else             out1[(size_t)r * D_INNER + (c - D_INNER)] = v;
            } else if (MODE == 1) {
                out0[(size_t)r * N + c] = softplus_f(v);
            } else {
                out0[(size_t)r * N + c] = v + aux[(size_t)r * N + c];
            }
        }
    }
}

// ---------------------------------------------------------------------------
// Depthwise causal conv1d (+bias) + silu. Layout (B*L, D_INNER), conv over L.
// ---------------------------------------------------------------------------
__global__ __launch_bounds__(256)
void conv_silu_kernel(const float* __restrict__ xi, const float* __restrict__ w,
                      const float* __restrict__ cb, float* __restrict__ xc, int total)
{
    const int i = blockIdx.x * 256 + threadIdx.x;
    if (i >= total) return;
    const int d = i & (D_INNER - 1);
    const int bl = i >> 11;            // D_INNER = 2048 = 2^11
    const int l = bl & 1023;           // L = 1024
    float acc = cb[d];
#pragma unroll
    for (int k = 0; k < D_CONV; k++) {
        const int li = l + k - (D_CONV - 1);
        if (li >= 0) acc = fmaf(w[d * D_CONV + k], xi[(size_t)i + (k - (D_CONV - 1)) * D_INNER], acc);
    }
    xc[i] = silu_f(acc);
}

// ---------------------------------------------------------------------------
// x_proj: bc(BL x 32) = xc(BL x 2048) @ W_xp(2048 x 32) + b_xp
// One block per row; 128 threads = 32 cols x 4 K-slices.
// ---------------------------------------------------------------------------
__global__ __launch_bounds__(128)
void xproj_kernel(const float* __restrict__ xc, const float* __restrict__ W,
                  const float* __restrict__ bxp, float* __restrict__ bc)
{
    const int row = blockIdx.x;
    const int c = threadIdx.x & 31, s = threadIdx.x >> 5;
    const float* xr = xc + (size_t)row * D_INNER;
    float acc = 0.f;
    for (int k = s * 512; k < (s + 1) * 512; k += 4) {
        const float4 xv = *(const float4*)&xr[k];
        acc = fmaf(xv.x, W[(k + 0) * 32 + c], acc);
        acc = fmaf(xv.y, W[(k + 1) * 32 + c], acc);
        acc = fmaf(xv.z, W[(k + 2) * 32 + c], acc);
        acc = fmaf(xv.w, W[(k + 3) * 32 + c], acc);
    }
    __shared__ float red[4][32];
    red[s][c] = acc;
    __syncthreads();
    if (s == 0)
        bc[(size_t)row * 32 + c] = red[0][c] + red[1][c] + red[2][c] + red[3][c] + bxp[c];
}

// ---------------------------------------------------------------------------
// SSM selective scan. One lane per (b, d) channel, 16 states in registers.
// B/C (bc) staged in LDS in chunks of 128 timesteps.
// Fused epilogue: y = (sum_n h*C + x*D) * silu(res).
// ---------------------------------------------------------------------------
__global__ __launch_bounds__(256)
void ssm_scan_kernel(const float* __restrict__ xc, const float* __restrict__ dt,
                     const float* __restrict__ bc, const float* __restrict__ A_log,
                     const float* __restrict__ Dp, const float* __restrict__ res,
                     float* __restrict__ y, int L)
{
    const int d = blockIdx.x * 256 + threadIdx.x;
    const int b = blockIdx.y;

    float Arow[D_STATE];
#pragma unroll
    for (int n = 0; n < D_STATE; n += 4) {
        const float4 a = *(const float4*)&A_log[(size_t)d * D_STATE + n];
        Arow[n + 0] = -__expf(a.x);
        Arow[n + 1] = -__expf(a.y);
        Arow[n + 2] = -__expf(a.z);
        Arow[n + 3] = -__expf(a.w);
    }
    const float Dv = Dp[d];
    float h[D_STATE] = {};

    __shared__ float sbc[128][32];  // 16 KiB: 128 timesteps of B(16)+C(16)

    for (int l0 = 0; l0 < L; l0 += 128) {
        __syncthreads();
        for (int t = threadIdx.x; t < 1024; t += 256) {   // 128*32/4 float4 loads
            const int r = t >> 3, cc = (t & 7) << 2;
            *(float4*)&sbc[r][cc] = *(const float4*)&bc[((size_t)(b * L + l0 + r)) * 32 + cc];
        }
        __syncthreads();
        for (int l = 0; l < 128; l++) {
            const size_t idx = ((size_t)(b * L + l0 + l)) * D_INNER + d;
            const float dtv = dt[idx];
            const float xv = xc[idx];
            const float dtx = dtv * xv;
            float yv = 0.f;
#pragma unroll
            for (int n = 0; n < D_STATE; n++) {
                const float a = __expf(dtv * Arow[n]);
                h[n] = fmaf(a, h[n], dtx * sbc[l][n]);
                yv = fmaf(h[n], sbc[l][16 + n], yv);
            }
            const float rv = res[idx];
            yv = (yv + xv * Dv) * silu_f(rv);
            y[idx] = yv;
        }
    }
}

// ---------------------------------------------------------------------------
// LayerNorm over D_MODEL=1024 per row. One block (256 threads) per row.
// ---------------------------------------------------------------------------
__global__ __launch_bounds__(256)
void layernorm_kernel(const float* __restrict__ z, const float* __restrict__ g,
                      const float* __restrict__ beta, float* __restrict__ out)
{
    const int row = blockIdx.x;
    const int tid = threadIdx.x;
    const float* zr = z + (size_t)row * D_MODEL;
    const float4 v = *(const float4*)&zr[tid << 2];
    float s = v.x + v.y + v.z + v.w;
    float ss = v.x * v.x + v.y * v.y + v.z * v.z + v.w * v.w;

    __shared__ float sm[256], sq[256];
    sm[tid] = s; sq[tid] = ss;
    __syncthreads();
    for (int off = 128; off > 0; off >>= 1) {
        if (tid < off) { sm[tid] += sm[tid + off]; sq[tid] += sq[tid + off]; }
        __syncthreads();
    }
    const float mean = sm[0] * (1.f / D_MODEL);
    const float var = sq[0] * (1.f / D_MODEL) - mean * mean;
    const float rstd = rsqrtf(var + 1e-5f);

    float4 o;
    o.x = (v.x - mean) * rstd * g[(tid << 2) + 0] + beta[(tid << 2) + 0];
    o.y = (v.y - mean) * rstd * g[(tid << 2) + 1] + beta[(tid << 2) + 1];
    o.z = (v.z - mean) * rstd * g[(tid << 2) + 2] + beta[(tid << 2) + 2];
    o.w = (v.w - mean) * rstd * g[(tid << 2) + 3] + beta[(tid << 2) + 3];
    *(float4*)&out[(size_t)row * D_MODEL + (tid << 2)] = o;
}

// ---------------------------------------------------------------------------
extern "C" void kernel_launch(void* const* d_in, const int* in_sizes, int n_in,
                              void* d_out, int out_size, void* d_ws, size_t ws_size,
                              hipStream_t stream)
{
    const float* x      = (const float*)d_in[0];   // (B,L,1024)
    const float* W_in   = (const float*)d_in[1];   // (1024, 4096)
    const float* b_in   = (const float*)d_in[2];   // (4096)
    const float* conv_w = (const float*)d_in[3];   // (2048,1,4)
    const float* conv_b = (const float*)d_in[4];   // (2048)
    const float* W_xp   = (const float*)d_in[5];   // (2048,32)
    const float* b_xp   = (const float*)d_in[6];   // (32)
    const float* W_dt   = (const float*)d_in[7];   // (2048,2048)
    const float* b_dt   = (const float*)d_in[8];   // (2048)
    const float* A_log  = (const float*)d_in[9];   // (2048,16)
    const float* D_par  = (const float*)d_in[10];  // (2048)
    const float* W_out  = (const float*)d_in[11];  // (2048,1024)
    const float* b_out  = (const float*)d_in[12];  // (1024)
    const float* ln_g   = (const float*)d_in[13];  // (1024)
    const float* ln_b   = (const float*)d_in[14];  // (1024)
    float* out = (float*)d_out;

    const int BL = in_sizes[0] / D_MODEL;   // 4096 tokens
    const int L = 1024;
    const int Bb = BL / L;                  // 4

    // workspace layout (floats). y reuses xi_act; z reuses dt.
    float* ws = (float*)d_ws;
    float* xi_act = ws;                                // BL*2048 (silu(in_proj x-half))
    float* res    = xi_act + (size_t)BL * D_INNER;     // BL*2048 (raw gate half)
    float* xc     = res    + (size_t)BL * D_INNER;     // BL*2048 (post conv+silu)
    float* dtb    = xc     + (size_t)BL * D_INNER;     // BL*2048 (softplus dt) -> later z
    float* bcb    = dtb    + (size_t)BL * D_INNER;     // BL*32   (B,C)
    float* ybuf   = xi_act;                            // scan output reuses xi_act
    float* zbuf   = dtb;                               // pre-LN reuses dt buffer

    // 1) in_proj: xr = x @ W_in + b_in; split + silu on x-half
    gemm_tiled<0><<<dim3(2 * D_INNER / 64, BL / 64), 256, 0, stream>>>(
        x, W_in, b_in, nullptr, xi_act, res, BL, 2 * D_INNER, D_MODEL);

    // 2) depthwise causal conv + silu
    conv_silu_kernel<<<(BL * D_INNER) / 256, 256, 0, stream>>>(
        xi_act, conv_w, conv_b, xc, BL * D_INNER);

    // 3) x_proj -> B,C
    xproj_kernel<<<BL, 128, 0, stream>>>(xc, W_xp, b_xp, bcb);

    // 4) dt = softplus(xc @ W_dt + b_dt)
    gemm_tiled<1><<<dim3(D_INNER / 64, BL / 64), 256, 0, stream>>>(
        xc, W_dt, b_dt, nullptr, dtb, nullptr, BL, D_INNER, D_INNER);

    // 5) selective scan (fused +x*D and *silu(res))
    ssm_scan_kernel<<<dim3(D_INNER / 256, Bb), 256, 0, stream>>>(
        xc, dtb, bcb, A_log, D_par, res, ybuf, L);

    // 6) out_proj + residual
    gemm_tiled<2><<<dim3(D_MODEL / 64, BL / 64), 256, 0, stream>>>(
        ybuf, W_out, b_out, x, zbuf, nullptr, BL, D_MODEL, D_INNER);

    // 7) LayerNorm
    layernorm_kernel<<<BL, 256, 0, stream>>>(zbuf, ln_g, ln_b, out);
}

// Round 3
// 578.716 us; speedup vs baseline: 3.4606x; 3.4606x over previous
//
#include <hip/hip_runtime.h>
#include <math.h>

#define D_MODEL 1024
#define D_INNER 2048
#define D_STATE 16
#define D_CONV  4

typedef unsigned short u16;
typedef __attribute__((ext_vector_type(8))) short short8;
typedef __attribute__((ext_vector_type(4))) float f32x4;
typedef __attribute__((ext_vector_type(4))) unsigned short u16x4;

__device__ __forceinline__ float silu_f(float x) { return x / (1.f + __expf(-x)); }
__device__ __forceinline__ float softplus_f(float x) {
    return fmaxf(x, 0.f) + log1pf(__expf(-fabsf(x)));
}
__device__ __forceinline__ u16 f2bf(float f) {
    union { float f; unsigned u; } c; c.f = f;
    unsigned r = c.u + 0x7fffu + ((c.u >> 16) & 1u);   // RNE
    return (u16)(r >> 16);
}
__device__ __forceinline__ void gload_lds16(const void* g, void* l) {
    __builtin_amdgcn_global_load_lds((const __attribute__((address_space(1))) void*)g,
                                     (__attribute__((address_space(3))) void*)l, 16, 0, 0);
}

// ---------------------------------------------------------------------------
// fp32 -> bf16 elementwise convert (4 elems/thread)
// ---------------------------------------------------------------------------
__global__ __launch_bounds__(256)
void f32_to_bf16_kernel(const float* __restrict__ in, u16* __restrict__ out, int n4)
{
    const int i = blockIdx.x * 256 + threadIdx.x;
    if (i >= n4) return;
    const float4 v = *(const float4*)&in[(size_t)i * 4];
    u16x4 o; o.x = f2bf(v.x); o.y = f2bf(v.y); o.z = f2bf(v.z); o.w = f2bf(v.w);
    *(u16x4*)&out[(size_t)i * 4] = o;
}

// ---------------------------------------------------------------------------
// W[K][N] fp32 -> Wt[N][K] bf16 (32x32 LDS tiles)
// ---------------------------------------------------------------------------
__global__ __launch_bounds__(256)
void transpose_bf16_kernel(const float* __restrict__ W, u16* __restrict__ Wt, int K, int N)
{
    __shared__ float tile[32][33];
    const int tx = threadIdx.x & 31, ty = threadIdx.x >> 5;
    const int n0 = blockIdx.x * 32, k0 = blockIdx.y * 32;
#pragma unroll
    for (int q = 0; q < 4; q++)
        tile[ty + q * 8][tx] = W[(size_t)(k0 + ty + q * 8) * N + n0 + tx];
    __syncthreads();
#pragma unroll
    for (int q = 0; q < 4; q++)
        Wt[(size_t)(n0 + ty + q * 8) * K + k0 + tx] = f2bf(tile[tx][ty + q * 8]);
}

// ---------------------------------------------------------------------------
// bf16 MFMA GEMM: C(MxN) = A(MxK) * Bt(NxK)^T + bias, fused epilogues (fp32 out).
// 128x128 tile, BK=32, 256 threads = 4 waves, each wave 64x64 (4x4 frags 16x16x32).
// MODE 0: col<D_INNER -> out0=silu(v) ; else out1=v      (in_proj)
// MODE 1: out0 = softplus(v)                             (dt_proj)
// MODE 2: out0 = v + aux[row*N+col]                      (out_proj + residual)
// ---------------------------------------------------------------------------
template <int MODE>
__global__ __launch_bounds__(256)
void gemm_mfma(const u16* __restrict__ A, const u16* __restrict__ Bt,
               const float* __restrict__ bias, const float* __restrict__ aux,
               float* __restrict__ out0, float* __restrict__ out1,
               int M, int N, int K)
{
    __shared__ __align__(16) short As[128 * 32];
    __shared__ __align__(16) short Bs[128 * 32];

    const int tid = threadIdx.x;
    const int wid = tid >> 6, lane = tid & 63;
    const int wr = wid >> 1, wc = wid & 1;
    const int row0 = blockIdx.y * 128, col0 = blockIdx.x * 128;

    f32x4 acc[4][4] = {};

    // staging: chunk c (16B = 8 bf16): row = c>>2, slot = c&3. 512 chunks per tile.
    const int c0 = wid * 128 + lane;   // call 0
    const int c1 = c0 + 64;            // call 1
    const u16* Abase = A + (size_t)row0 * K;
    const u16* Bbase = Bt + (size_t)col0 * K;

    const int kg = lane >> 4, r16 = lane & 15;

    for (int k0 = 0; k0 < K; k0 += 32) {
        __syncthreads();   // previous compute done before overwrite
        gload_lds16(Abase + (size_t)(c0 >> 2) * K + k0 + (c0 & 3) * 8, &As[wid * 1024]);
        gload_lds16(Abase + (size_t)(c1 >> 2) * K + k0 + (c1 & 3) * 8, &As[wid * 1024 + 512]);
        gload_lds16(Bbase + (size_t)(c0 >> 2) * K + k0 + (c0 & 3) * 8, &Bs[wid * 1024]);
        gload_lds16(Bbase + (size_t)(c1 >> 2) * K + k0 + (c1 & 3) * 8, &Bs[wid * 1024 + 512]);
        __syncthreads();   // drains vmcnt -> LDS tile ready

        short8 af[4], bg[4];
#pragma unroll
        for (int i = 0; i < 4; i++)
            af[i] = *(const short8*)&As[(wr * 64 + i * 16 + r16) * 32 + kg * 8];
#pragma unroll
        for (int j = 0; j < 4; j++)
            bg[j] = *(const short8*)&Bs[(wc * 64 + j * 16 + r16) * 32 + kg * 8];
#pragma unroll
        for (int i = 0; i < 4; i++)
#pragma unroll
            for (int j = 0; j < 4; j++)
                acc[i][j] = __builtin_amdgcn_mfma_f32_16x16x32_bf16(af[i], bg[j], acc[i][j], 0, 0, 0);
    }

    // epilogue: D layout col = lane&15, row = (lane>>4)*4 + reg
#pragma unroll
    for (int i = 0; i < 4; i++) {
#pragma unroll
        for (int j = 0; j < 4; j++) {
#pragma unroll
            for (int r = 0; r < 4; r++) {
                const int row = row0 + wr * 64 + i * 16 + kg * 4 + r;
                const int col = col0 + wc * 64 + j * 16 + r16;
                float v = acc[i][j][r] + bias[col];
                if (MODE == 0) {
                    if (col < D_INNER) out0[(size_t)row * D_INNER + col] = silu_f(v);
                    else               out1[(size_t)row * D_INNER + (col - D_INNER)] = v;
                } else if (MODE == 1) {
                    out0[(size_t)row * N + col] = softplus_f(v);
                } else {
                    out0[(size_t)row * N + col] = v + aux[(size_t)row * N + col];
                }
            }
        }
    }
}

// ---------------------------------------------------------------------------
// Depthwise causal conv1d (+bias) + silu. Writes fp32 and bf16 copies.
// ---------------------------------------------------------------------------
__global__ __launch_bounds__(256)
void conv_silu_kernel(const float* __restrict__ xi, const float* __restrict__ w,
                      const float* __restrict__ cb, float* __restrict__ xc,
                      u16* __restrict__ xcb, int total)
{
    const int i = blockIdx.x * 256 + threadIdx.x;
    if (i >= total) return;
    const int d = i & (D_INNER - 1);
    const int bl = i >> 11;
    const int l = bl & 1023;
    float acc = cb[d];
#pragma unroll
    for (int k = 0; k < D_CONV; k++) {
        const int li = l + k - (D_CONV - 1);
        if (li >= 0) acc = fmaf(w[d * D_CONV + k], xi[(size_t)i + (k - (D_CONV - 1)) * D_INNER], acc);
    }
    const float s = silu_f(acc);
    xc[i] = s;
    xcb[i] = f2bf(s);
}

// ---------------------------------------------------------------------------
// x_proj: bc(BL x 32) = xc(BL x 2048) @ W_xp(2048 x 32) + b_xp   (fp32)
// ---------------------------------------------------------------------------
__global__ __launch_bounds__(128)
void xproj_kernel(const float* __restrict__ xc, const float* __restrict__ W,
                  const float* __restrict__ bxp, float* __restrict__ bc)
{
    const int row = blockIdx.x;
    const int c = threadIdx.x & 31, s = threadIdx.x >> 5;
    const float* xr = xc + (size_t)row * D_INNER;
    float acc = 0.f;
    for (int k = s * 512; k < (s + 1) * 512; k += 4) {
        const float4 xv = *(const float4*)&xr[k];
        acc = fmaf(xv.x, W[(k + 0) * 32 + c], acc);
        acc = fmaf(xv.y, W[(k + 1) * 32 + c], acc);
        acc = fmaf(xv.z, W[(k + 2) * 32 + c], acc);
        acc = fmaf(xv.w, W[(k + 3) * 32 + c], acc);
    }
    __shared__ float red[4][32];
    red[s][c] = acc;
    __syncthreads();
    if (s == 0)
        bc[(size_t)row * 32 + c] = red[0][c] + red[1][c] + red[2][c] + red[3][c] + bxp[c];
}

// ---------------------------------------------------------------------------
// SSM selective scan, one thread per (b, d, n-state): 131072 threads.
// Block = 16 channels x 16 states. Shuffle-reduce over n. Output y in bf16.
// ---------------------------------------------------------------------------
__global__ __launch_bounds__(256)
void ssm_scan_kernel(const float* __restrict__ xc, const float* __restrict__ dt,
                     const float* __restrict__ bc, const float* __restrict__ A_log,
                     const float* __restrict__ Dp, const float* __restrict__ res,
                     u16* __restrict__ ybf)
{
    const int tid = threadIdx.x;
    const int ch = tid >> 4, n = tid & 15;
    const int d0 = blockIdx.x * 16;
    const int b = blockIdx.y;
    const int d = d0 + ch;

    const float Aln = -__expf(A_log[d * D_STATE + n]);
    const float Dv = Dp[d];

    __shared__ float sdt[64][20], sxc[64][20], sres[64][20], sy[64][20];
    __shared__ float sbc[64][32];

    float h = 0.f;

    for (int l0 = 0; l0 < 1024; l0 += 64) {
        __syncthreads();
        {
            const int l = tid >> 2, di = (tid & 3) << 2;
            const size_t g = ((size_t)(b * 1024 + l0 + l)) * D_INNER + d0 + di;
            *(float4*)&sdt[l][di] = *(const float4*)&dt[g];
            *(float4*)&sxc[l][di] = *(const float4*)&xc[g];
            *(float4*)&sres[l][di] = *(const float4*)&res[g];
            const int lb = tid >> 3, cb4 = (tid & 7) << 2;
            const size_t gb = ((size_t)(b * 1024 + l0 + lb)) * 32 + cb4;
            *(float4*)&sbc[lb][cb4] = *(const float4*)&bc[gb];
            *(float4*)&sbc[lb + 32][cb4] = *(const float4*)&bc[gb + 32 * 32];
        }
        __syncthreads();
        for (int l = 0; l < 64; ++l) {
            const float dtv = sdt[l][ch];
            const float xv = sxc[l][ch];
            const float a = __expf(dtv * Aln);
            const float u = dtv * xv * sbc[l][n];
            h = fmaf(a, h, u);
            float p = h * sbc[l][16 + n];
            p += __shfl_xor(p, 1);
            p += __shfl_xor(p, 2);
            p += __shfl_xor(p, 4);
            p += __shfl_xor(p, 8);
            if (n == 0) {
                const float rv = sres[l][ch];
                sy[l][ch] = (p + xv * Dv) * silu_f(rv);
            }
        }
        __syncthreads();
        {
            const int l = tid >> 2, di = (tid & 3) << 2;
            const size_t g = ((size_t)(b * 1024 + l0 + l)) * D_INNER + d0 + di;
            u16x4 o;
            o.x = f2bf(sy[l][di + 0]); o.y = f2bf(sy[l][di + 1]);
            o.z = f2bf(sy[l][di + 2]); o.w = f2bf(sy[l][di + 3]);
            *(u16x4*)&ybf[g] = o;
        }
    }
}

// ---------------------------------------------------------------------------
// LayerNorm over D_MODEL=1024 per row.
// ---------------------------------------------------------------------------
__global__ __launch_bounds__(256)
void layernorm_kernel(const float* __restrict__ z, const float* __restrict__ g,
                      const float* __restrict__ beta, float* __restrict__ out)
{
    const int row = blockIdx.x;
    const int tid = threadIdx.x;
    const float* zr = z + (size_t)row * D_MODEL;
    const float4 v = *(const float4*)&zr[tid << 2];
    float s = v.x + v.y + v.z + v.w;
    float ss = v.x * v.x + v.y * v.y + v.z * v.z + v.w * v.w;

    __shared__ float sm[256], sq[256];
    sm[tid] = s; sq[tid] = ss;
    __syncthreads();
    for (int off = 128; off > 0; off >>= 1) {
        if (tid < off) { sm[tid] += sm[tid + off]; sq[tid] += sq[tid + off]; }
        __syncthreads();
    }
    const float mean = sm[0] * (1.f / D_MODEL);
    const float var = sq[0] * (1.f / D_MODEL) - mean * mean;
    const float rstd = rsqrtf(var + 1e-5f);

    float4 o;
    o.x = (v.x - mean) * rstd * g[(tid << 2) + 0] + beta[(tid << 2) + 0];
    o.y = (v.y - mean) * rstd * g[(tid << 2) + 1] + beta[(tid << 2) + 1];
    o.z = (v.z - mean) * rstd * g[(tid << 2) + 2] + beta[(tid << 2) + 2];
    o.w = (v.w - mean) * rstd * g[(tid << 2) + 3] + beta[(tid << 2) + 3];
    *(float4*)&out[(size_t)row * D_MODEL + (tid << 2)] = o;
}

// ---------------------------------------------------------------------------
extern "C" void kernel_launch(void* const* d_in, const int* in_sizes, int n_in,
                              void* d_out, int out_size, void* d_ws, size_t ws_size,
                              hipStream_t stream)
{
    const float* x      = (const float*)d_in[0];
    const float* W_in   = (const float*)d_in[1];
    const float* b_in   = (const float*)d_in[2];
    const float* conv_w = (const float*)d_in[3];
    const float* conv_b = (const float*)d_in[4];
    const float* W_xp   = (const float*)d_in[5];
    const float* b_xp   = (const float*)d_in[6];
    const float* W_dt   = (const float*)d_in[7];
    const float* b_dt   = (const float*)d_in[8];
    const float* A_log  = (const float*)d_in[9];
    const float* D_par  = (const float*)d_in[10];
    const float* W_out  = (const float*)d_in[11];
    const float* b_out  = (const float*)d_in[12];
    const float* ln_g   = (const float*)d_in[13];
    const float* ln_b   = (const float*)d_in[14];
    float* out = (float*)d_out;

    const int BL = in_sizes[0] / D_MODEL;   // 4096
    const int Bb = BL / 1024;               // 4
    const size_t BLD = (size_t)BL * D_INNER;

    // workspace layout
    float* ws = (float*)d_ws;
    float* xi_act = ws;                     // BLD f32 ; later reused (as u16) by ybf
    float* resb   = ws + BLD;               // BLD f32
    float* xcb    = ws + 2 * BLD;           // BLD f32
    float* dtb    = ws + 3 * BLD;           // BLD f32 ; later zbuf
    float* bcbuf  = ws + 4 * BLD;           // BL*32 f32
    u16*   xbf    = (u16*)(ws + 4 * BLD + (size_t)BL * 32);  // BL*1024 u16
    u16*   xcbf   = xbf + (size_t)BL * D_MODEL;              // BLD u16
    u16*   wtmp   = xcbf + BLD;                              // up to 4M u16 (shared W buffer)
    u16*   ybf    = (u16*)xi_act;
    float* zbuf   = dtb;

    // 1) x -> bf16
    f32_to_bf16_kernel<<<(BL * D_MODEL / 4 + 255) / 256, 256, 0, stream>>>(x, xbf, BL * D_MODEL / 4);

    // 2) W_in (1024x4096) -> Wt bf16 (4096x1024)
    transpose_bf16_kernel<<<dim3(2 * D_INNER / 32, D_MODEL / 32), 256, 0, stream>>>(W_in, wtmp, D_MODEL, 2 * D_INNER);

    // 3) in_proj GEMM (bf16 MFMA): silu-half + gate-half
    gemm_mfma<0><<<dim3(2 * D_INNER / 128, BL / 128), 256, 0, stream>>>(
        xbf, wtmp, b_in, nullptr, xi_act, resb, BL, 2 * D_INNER, D_MODEL);

    // 4) depthwise causal conv + silu (fp32 + bf16 outputs)
    conv_silu_kernel<<<(int)(BLD / 256), 256, 0, stream>>>(
        xi_act, conv_w, conv_b, xcb, xcbf, (int)BLD);

    // 5) x_proj -> B,C (fp32)
    xproj_kernel<<<BL, 128, 0, stream>>>(xcb, W_xp, b_xp, bcbuf);

    // 6) W_dt (2048x2048) -> Wt bf16
    transpose_bf16_kernel<<<dim3(D_INNER / 32, D_INNER / 32), 256, 0, stream>>>(W_dt, wtmp, D_INNER, D_INNER);

    // 7) dt_proj GEMM (bf16 MFMA) + softplus
    gemm_mfma<1><<<dim3(D_INNER / 128, BL / 128), 256, 0, stream>>>(
        xcbf, wtmp, b_dt, nullptr, dtb, nullptr, BL, D_INNER, D_INNER);

    // 8) selective scan (exact fp32 recurrence; bf16 y out)
    ssm_scan_kernel<<<dim3(D_INNER / 16, Bb), 256, 0, stream>>>(
        xcb, dtb, bcbuf, A_log, D_par, resb, ybf);

    // 9) W_out (2048x1024) -> Wt bf16
    transpose_bf16_kernel<<<dim3(D_MODEL / 32, D_INNER / 32), 256, 0, stream>>>(W_out, wtmp, D_INNER, D_MODEL);

    // 10) out_proj GEMM (bf16 MFMA) + bias + residual
    gemm_mfma<2><<<dim3(D_MODEL / 128, BL / 128), 256, 0, stream>>>(
        ybf, wtmp, b_out, x, zbuf, nullptr, BL, D_MODEL, D_INNER);

    // 11) LayerNorm
    layernorm_kernel<<<BL, 256, 0, stream>>>(zbuf, ln_g, ln_b, out);
}

// Round 4
// 419.789 us; speedup vs baseline: 4.7707x; 1.3786x over previous
//
#include <hip/hip_runtime.h>
#include <math.h>

#define D_MODEL 1024
#define D_INNER 2048
#define D_STATE 16
#define D_CONV  4
#define NCHUNK  8
#define LCHUNK  128

typedef unsigned short u16;
typedef __attribute__((ext_vector_type(8))) short short8;
typedef __attribute__((ext_vector_type(4))) float f32x4;
typedef __attribute__((ext_vector_type(4))) unsigned short u16x4;

__device__ __forceinline__ float silu_f(float x) { return x / (1.f + __expf(-x)); }
__device__ __forceinline__ float softplus_f(float x) {
    return fmaxf(x, 0.f) + log1pf(__expf(-fabsf(x)));
}
__device__ __forceinline__ u16 f2bf(float f) {
    union { float f; unsigned u; } c; c.f = f;
    unsigned r = c.u + 0x7fffu + ((c.u >> 16) & 1u);   // RNE
    return (u16)(r >> 16);
}
__device__ __forceinline__ void gload_lds16(const void* g, void* l) {
    __builtin_amdgcn_global_load_lds((const __attribute__((address_space(1))) void*)g,
                                     (__attribute__((address_space(3))) void*)l, 16, 0, 0);
}

// ---------------------------------------------------------------------------
// fp32 -> bf16 elementwise convert (4 elems/thread)
// ---------------------------------------------------------------------------
__global__ __launch_bounds__(256)
void f32_to_bf16_kernel(const float* __restrict__ in, u16* __restrict__ out, int n4)
{
    const int i = blockIdx.x * 256 + threadIdx.x;
    if (i >= n4) return;
    const float4 v = *(const float4*)&in[(size_t)i * 4];
    u16x4 o; o.x = f2bf(v.x); o.y = f2bf(v.y); o.z = f2bf(v.z); o.w = f2bf(v.w);
    *(u16x4*)&out[(size_t)i * 4] = o;
}

// ---------------------------------------------------------------------------
// W[K][N] fp32 -> Wt[N][K] bf16 (32x32 LDS tiles)
// ---------------------------------------------------------------------------
__global__ __launch_bounds__(256)
void transpose_bf16_kernel(const float* __restrict__ W, u16* __restrict__ Wt, int K, int N)
{
    __shared__ float tile[32][33];
    const int tx = threadIdx.x & 31, ty = threadIdx.x >> 5;
    const int n0 = blockIdx.x * 32, k0 = blockIdx.y * 32;
#pragma unroll
    for (int q = 0; q < 4; q++)
        tile[ty + q * 8][tx] = W[(size_t)(k0 + ty + q * 8) * N + n0 + tx];
    __syncthreads();
#pragma unroll
    for (int q = 0; q < 4; q++)
        Wt[(size_t)(n0 + ty + q * 8) * K + k0 + tx] = f2bf(tile[tx][ty + q * 8]);
}

// ---------------------------------------------------------------------------
// bf16 MFMA GEMM: C(MxN) = A(MxK) * Bt(NxK)^T + bias, fused epilogues (fp32 out).
// 128x128 tile, BK=32, 256 threads = 4 waves, each wave 64x64 (4x4 frags 16x16x32).
// ---------------------------------------------------------------------------
template <int MODE>
__global__ __launch_bounds__(256)
void gemm_mfma(const u16* __restrict__ A, const u16* __restrict__ Bt,
               const float* __restrict__ bias, const float* __restrict__ aux,
               float* __restrict__ out0, float* __restrict__ out1,
               int M, int N, int K)
{
    __shared__ __align__(16) short As[128 * 32];
    __shared__ __align__(16) short Bs[128 * 32];

    const int tid = threadIdx.x;
    const int wid = tid >> 6, lane = tid & 63;
    const int wr = wid >> 1, wc = wid & 1;
    const int row0 = blockIdx.y * 128, col0 = blockIdx.x * 128;

    f32x4 acc[4][4] = {};

    const int c0 = wid * 128 + lane;
    const int c1 = c0 + 64;
    const u16* Abase = A + (size_t)row0 * K;
    const u16* Bbase = Bt + (size_t)col0 * K;

    const int kg = lane >> 4, r16 = lane & 15;

    for (int k0 = 0; k0 < K; k0 += 32) {
        __syncthreads();
        gload_lds16(Abase + (size_t)(c0 >> 2) * K + k0 + (c0 & 3) * 8, &As[wid * 1024]);
        gload_lds16(Abase + (size_t)(c1 >> 2) * K + k0 + (c1 & 3) * 8, &As[wid * 1024 + 512]);
        gload_lds16(Bbase + (size_t)(c0 >> 2) * K + k0 + (c0 & 3) * 8, &Bs[wid * 1024]);
        gload_lds16(Bbase + (size_t)(c1 >> 2) * K + k0 + (c1 & 3) * 8, &Bs[wid * 1024 + 512]);
        __syncthreads();

        short8 af[4], bg[4];
#pragma unroll
        for (int i = 0; i < 4; i++)
            af[i] = *(const short8*)&As[(wr * 64 + i * 16 + r16) * 32 + kg * 8];
#pragma unroll
        for (int j = 0; j < 4; j++)
            bg[j] = *(const short8*)&Bs[(wc * 64 + j * 16 + r16) * 32 + kg * 8];
#pragma unroll
        for (int i = 0; i < 4; i++)
#pragma unroll
            for (int j = 0; j < 4; j++)
                acc[i][j] = __builtin_amdgcn_mfma_f32_16x16x32_bf16(af[i], bg[j], acc[i][j], 0, 0, 0);
    }

#pragma unroll
    for (int i = 0; i < 4; i++) {
#pragma unroll
        for (int j = 0; j < 4; j++) {
#pragma unroll
            for (int r = 0; r < 4; r++) {
                const int row = row0 + wr * 64 + i * 16 + kg * 4 + r;
                const int col = col0 + wc * 64 + j * 16 + r16;
                float v = acc[i][j][r] + bias[col];
                if (MODE == 0) {
                    if (col < D_INNER) out0[(size_t)row * D_INNER + col] = silu_f(v);
                    else               out1[(size_t)row * D_INNER + (col - D_INNER)] = v;
                } else if (MODE == 1) {
                    out0[(size_t)row * N + col] = softplus_f(v);
                } else {
                    out0[(size_t)row * N + col] = v + aux[(size_t)row * N + col];
                }
            }
        }
    }
}

// ---------------------------------------------------------------------------
// Depthwise causal conv1d (+bias) + silu. Writes fp32 and bf16 copies.
// ---------------------------------------------------------------------------
__global__ __launch_bounds__(256)
void conv_silu_kernel(const float* __restrict__ xi, const float* __restrict__ w,
                      const float* __restrict__ cb, float* __restrict__ xc,
                      u16* __restrict__ xcb, int total)
{
    const int i = blockIdx.x * 256 + threadIdx.x;
    if (i >= total) return;
    const int d = i & (D_INNER - 1);
    const int bl = i >> 11;
    const int l = bl & 1023;
    float acc = cb[d];
#pragma unroll
    for (int k = 0; k < D_CONV; k++) {
        const int li = l + k - (D_CONV - 1);
        if (li >= 0) acc = fmaf(w[d * D_CONV + k], xi[(size_t)i + (k - (D_CONV - 1)) * D_INNER], acc);
    }
    const float s = silu_f(acc);
    xc[i] = s;
    xcb[i] = f2bf(s);
}

// ---------------------------------------------------------------------------
// x_proj: bc(BL x 32) = xc(BL x 2048) @ W_xp(2048 x 32) + b_xp   (fp32)
// ---------------------------------------------------------------------------
__global__ __launch_bounds__(128)
void xproj_kernel(const float* __restrict__ xc, const float* __restrict__ W,
                  const float* __restrict__ bxp, float* __restrict__ bc)
{
    const int row = blockIdx.x;
    const int c = threadIdx.x & 31, s = threadIdx.x >> 5;
    const float* xr = xc + (size_t)row * D_INNER;
    float acc = 0.f;
    for (int k = s * 512; k < (s + 1) * 512; k += 4) {
        const float4 xv = *(const float4*)&xr[k];
        acc = fmaf(xv.x, W[(k + 0) * 32 + c], acc);
        acc = fmaf(xv.y, W[(k + 1) * 32 + c], acc);
        acc = fmaf(xv.z, W[(k + 2) * 32 + c], acc);
        acc = fmaf(xv.w, W[(k + 3) * 32 + c], acc);
    }
    __shared__ float red[4][32];
    red[s][c] = acc;
    __syncthreads();
    if (s == 0)
        bc[(size_t)row * 32 + c] = red[0][c] + red[1][c] + red[2][c] + red[3][c] + bxp[c];
}

// ---------------------------------------------------------------------------
// SSM scan phase 1: per (b, d, n, chunk) compute chunk-local end state
// (h starting from 0) and the chunk dt-sum. Block: 16 ch x 16 n, one chunk.
// ---------------------------------------------------------------------------
__global__ __launch_bounds__(256)
void ssm_s1_kernel(const float* __restrict__ xc, const float* __restrict__ dt,
                   const float* __restrict__ bc, const float* __restrict__ A_log,
                   float* __restrict__ hend, float* __restrict__ dtsum)
{
    const int tid = threadIdx.x;
    const int ch = tid >> 4, n = tid & 15;
    const int d0 = blockIdx.x * 16;
    const int c = blockIdx.y;
    const int b = blockIdx.z;
    const int d = d0 + ch;

    const float Aln = -__expf(A_log[d * D_STATE + n]);

    __shared__ float sdt[64][16], sdtx[64][16], sB[64][16];

    float h = 0.f, S = 0.f;

    for (int half = 0; half < 2; half++) {
        const int l0 = c * LCHUNK + half * 64;
        __syncthreads();
        {
            const int l = tid >> 2, di = (tid & 3) << 2;
            const size_t g = ((size_t)(b * 1024 + l0 + l)) * D_INNER + d0 + di;
            const float4 dv = *(const float4*)&dt[g];
            const float4 xv = *(const float4*)&xc[g];
            float4 dx;
            dx.x = dv.x * xv.x; dx.y = dv.y * xv.y; dx.z = dv.z * xv.z; dx.w = dv.w * xv.w;
            *(float4*)&sdt[l][di] = dv;
            *(float4*)&sdtx[l][di] = dx;
            *(float4*)&sB[l][di] = *(const float4*)&bc[((size_t)(b * 1024 + l0 + l)) * 32 + di];
        }
        __syncthreads();
#pragma unroll 16
        for (int l = 0; l < 64; l++) {
            const float dtv = sdt[l][ch];
            const float a = __expf(dtv * Aln);
            h = fmaf(a, h, sdtx[l][ch] * sB[l][n]);
            S += dtv;
        }
    }
    hend[((size_t)(b * NCHUNK + c) * D_INNER + d) * D_STATE + n] = h;
    if (n == 0) dtsum[(size_t)(b * NCHUNK + c) * D_INNER + d] = S;
}

// ---------------------------------------------------------------------------
// SSM scan phase 3: combine h_in from predecessor chunks (P = exp(A*dtsum)),
// rerun recurrence, emit y via per-wave LDS p-buffer (no shuffles, no barrier).
// y = (sum_n h*C + x*D) * silu(res), bf16 out.
// ---------------------------------------------------------------------------
__global__ __launch_bounds__(256)
void ssm_s3_kernel(const float* __restrict__ xc, const float* __restrict__ dt,
                   const float* __restrict__ bc, const float* __restrict__ A_log,
                   const float* __restrict__ Dp, const float* __restrict__ res,
                   const float* __restrict__ hend, const float* __restrict__ dtsum,
                   u16* __restrict__ ybf)
{
    const int tid = threadIdx.x;
    const int wid = tid >> 6, lane = tid & 63;
    const int ch4 = lane >> 4, n = lane & 15;
    const int ch = wid * 4 + ch4;
    const int d0 = blockIdx.x * 16;
    const int c = blockIdx.y;
    const int b = blockIdx.z;
    const int d = d0 + ch;

    const float Aln = -__expf(A_log[d * D_STATE + n]);
    const float Dv = Dp[d];

    // combine: h_in for chunk c
    float h = 0.f;
    for (int cc = 0; cc < c; cc++) {
        const float S = dtsum[(size_t)(b * NCHUNK + cc) * D_INNER + d];
        const float P = __expf(Aln * S);
        h = fmaf(P, h, hend[((size_t)(b * NCHUNK + cc) * D_INNER + d) * D_STATE + n]);
    }

    __shared__ float sdt[64][16], sdtx[64][16], sx[64][16], sres[64][16];
    __shared__ float sbc[64][32];
    __shared__ float pbuf[4 * 16 * 68];   // per-wave [16 j][4 ch4][16 n] stride 68

    float* pw = &pbuf[wid * 16 * 68];

    for (int half = 0; half < 2; half++) {
        const int l0 = c * LCHUNK + half * 64;
        __syncthreads();
        {
            const int l = tid >> 2, di = (tid & 3) << 2;
            const size_t g = ((size_t)(b * 1024 + l0 + l)) * D_INNER + d0 + di;
            const float4 dv = *(const float4*)&dt[g];
            const float4 xv = *(const float4*)&xc[g];
            const float4 rv = *(const float4*)&res[g];
            float4 dx;
            dx.x = dv.x * xv.x; dx.y = dv.y * xv.y; dx.z = dv.z * xv.z; dx.w = dv.w * xv.w;
            *(float4*)&sdt[l][di] = dv;
            *(float4*)&sdtx[l][di] = dx;
            *(float4*)&sx[l][di] = xv;
            *(float4*)&sres[l][di] = rv;
            // stage B,C: 64 rows x 32 -> 512 float4, 2 per thread
            const int r0 = tid >> 3, c4 = (tid & 7) << 2;
            *(float4*)&sbc[r0][c4] = *(const float4*)&bc[((size_t)(b * 1024 + l0 + r0)) * 32 + c4];
            const int r1 = (tid + 256) >> 3;
            *(float4*)&sbc[r1][c4] = *(const float4*)&bc[((size_t)(b * 1024 + l0 + r1)) * 32 + c4];
        }
        __syncthreads();

        for (int l16 = 0; l16 < 4; l16++) {
#pragma unroll
            for (int j = 0; j < 16; j++) {
                const int l = l16 * 16 + j;
                const float dtv = sdt[l][ch];
                const float a = __expf(dtv * Aln);
                h = fmaf(a, h, sdtx[l][ch] * sbc[l][n]);
                pw[j * 68 + ch4 * 16 + n] = h * sbc[l][16 + n];
            }
            __builtin_amdgcn_wave_barrier();
            // lane (ch4, n) reduces timestep (l16*16 + n) of channel ch over 16 states
            const float4 q0 = *(const float4*)&pw[n * 68 + ch4 * 16 + 0];
            const float4 q1 = *(const float4*)&pw[n * 68 + ch4 * 16 + 4];
            const float4 q2 = *(const float4*)&pw[n * 68 + ch4 * 16 + 8];
            const float4 q3 = *(const float4*)&pw[n * 68 + ch4 * 16 + 12];
            const float sum = ((q0.x + q0.y) + (q0.z + q0.w)) + ((q1.x + q1.y) + (q1.z + q1.w))
                            + ((q2.x + q2.y) + (q2.z + q2.w)) + ((q3.x + q3.y) + (q3.z + q3.w));
            const int t = l16 * 16 + n;
            const float xv = sx[t][ch];
            const float rv = sres[t][ch];
            const float yv = (sum + xv * Dv) * silu_f(rv);
            ybf[((size_t)(b * 1024 + l0 + t)) * D_INNER + d] = f2bf(yv);
            __builtin_amdgcn_wave_barrier();
        }
    }
}

// ---------------------------------------------------------------------------
// LayerNorm over D_MODEL=1024 per row.
// ---------------------------------------------------------------------------
__global__ __launch_bounds__(256)
void layernorm_kernel(const float* __restrict__ z, const float* __restrict__ g,
                      const float* __restrict__ beta, float* __restrict__ out)
{
    const int row = blockIdx.x;
    const int tid = threadIdx.x;
    const float* zr = z + (size_t)row * D_MODEL;
    const float4 v = *(const float4*)&zr[tid << 2];
    float s = v.x + v.y + v.z + v.w;
    float ss = v.x * v.x + v.y * v.y + v.z * v.z + v.w * v.w;

    __shared__ float sm[256], sq[256];
    sm[tid] = s; sq[tid] = ss;
    __syncthreads();
    for (int off = 128; off > 0; off >>= 1) {
        if (tid < off) { sm[tid] += sm[tid + off]; sq[tid] += sq[tid + off]; }
        __syncthreads();
    }
    const float mean = sm[0] * (1.f / D_MODEL);
    const float var = sq[0] * (1.f / D_MODEL) - mean * mean;
    const float rstd = rsqrtf(var + 1e-5f);

    float4 o;
    o.x = (v.x - mean) * rstd * g[(tid << 2) + 0] + beta[(tid << 2) + 0];
    o.y = (v.y - mean) * rstd * g[(tid << 2) + 1] + beta[(tid << 2) + 1];
    o.z = (v.z - mean) * rstd * g[(tid << 2) + 2] + beta[(tid << 2) + 2];
    o.w = (v.w - mean) * rstd * g[(tid << 2) + 3] + beta[(tid << 2) + 3];
    *(float4*)&out[(size_t)row * D_MODEL + (tid << 2)] = o;
}

// ---------------------------------------------------------------------------
extern "C" void kernel_launch(void* const* d_in, const int* in_sizes, int n_in,
                              void* d_out, int out_size, void* d_ws, size_t ws_size,
                              hipStream_t stream)
{
    const float* x      = (const float*)d_in[0];
    const float* W_in   = (const float*)d_in[1];
    const float* b_in   = (const float*)d_in[2];
    const float* conv_w = (const float*)d_in[3];
    const float* conv_b = (const float*)d_in[4];
    const float* W_xp   = (const float*)d_in[5];
    const float* b_xp   = (const float*)d_in[6];
    const float* W_dt   = (const float*)d_in[7];
    const float* b_dt   = (const float*)d_in[8];
    const float* A_log  = (const float*)d_in[9];
    const float* D_par  = (const float*)d_in[10];
    const float* W_out  = (const float*)d_in[11];
    const float* b_out  = (const float*)d_in[12];
    const float* ln_g   = (const float*)d_in[13];
    const float* ln_b   = (const float*)d_in[14];
    float* out = (float*)d_out;

    const int BL = in_sizes[0] / D_MODEL;   // 4096
    const int Bb = BL / 1024;               // 4
    const size_t BLD = (size_t)BL * D_INNER;

    // workspace layout
    float* ws = (float*)d_ws;
    float* xi_act = ws;                     // BLD f32 ; later reused (as u16) by ybf
    float* resb   = ws + BLD;               // BLD f32
    float* xcb    = ws + 2 * BLD;           // BLD f32
    float* dtb    = ws + 3 * BLD;           // BLD f32 ; later zbuf
    float* bcbuf  = ws + 4 * BLD;           // BL*32 f32
    u16*   xbf    = (u16*)(ws + 4 * BLD + (size_t)BL * 32);  // BL*1024 u16
    u16*   xcbf   = xbf + (size_t)BL * D_MODEL;              // BLD u16
    u16*   wtmp   = xcbf + BLD;                              // up to 4M u16
    float* hend   = (float*)(wtmp + (size_t)4 * 1024 * 1024); // B*NCHUNK*D_INNER*16
    float* dtsum  = hend + (size_t)Bb * NCHUNK * D_INNER * D_STATE; // B*NCHUNK*D_INNER
    u16*   ybf    = (u16*)xi_act;
    float* zbuf   = dtb;

    // 1) x -> bf16
    f32_to_bf16_kernel<<<(BL * D_MODEL / 4 + 255) / 256, 256, 0, stream>>>(x, xbf, BL * D_MODEL / 4);

    // 2) W_in (1024x4096) -> Wt bf16 (4096x1024)
    transpose_bf16_kernel<<<dim3(2 * D_INNER / 32, D_MODEL / 32), 256, 0, stream>>>(W_in, wtmp, D_MODEL, 2 * D_INNER);

    // 3) in_proj GEMM (bf16 MFMA): silu-half + gate-half
    gemm_mfma<0><<<dim3(2 * D_INNER / 128, BL / 128), 256, 0, stream>>>(
        xbf, wtmp, b_in, nullptr, xi_act, resb, BL, 2 * D_INNER, D_MODEL);

    // 4) depthwise causal conv + silu (fp32 + bf16 outputs)
    conv_silu_kernel<<<(int)(BLD / 256), 256, 0, stream>>>(
        xi_act, conv_w, conv_b, xcb, xcbf, (int)BLD);

    // 5) x_proj -> B,C (fp32)
    xproj_kernel<<<BL, 128, 0, stream>>>(xcb, W_xp, b_xp, bcbuf);

    // 6) W_dt (2048x2048) -> Wt bf16
    transpose_bf16_kernel<<<dim3(D_INNER / 32, D_INNER / 32), 256, 0, stream>>>(W_dt, wtmp, D_INNER, D_INNER);

    // 7) dt_proj GEMM (bf16 MFMA) + softplus
    gemm_mfma<1><<<dim3(D_INNER / 128, BL / 128), 256, 0, stream>>>(
        xcbf, wtmp, b_dt, nullptr, dtb, nullptr, BL, D_INNER, D_INNER);

    // 8a) scan phase 1: chunk-local end states + dt sums
    ssm_s1_kernel<<<dim3(D_INNER / 16, NCHUNK, Bb), 256, 0, stream>>>(
        xcb, dtb, bcbuf, A_log, hend, dtsum);

    // 8b) scan phase 3: combine + rerun + emit y (bf16)
    ssm_s3_kernel<<<dim3(D_INNER / 16, NCHUNK, Bb), 256, 0, stream>>>(
        xcb, dtb, bcbuf, A_log, D_par, resb, hend, dtsum, ybf);

    // 9) W_out (2048x1024) -> Wt bf16
    transpose_bf16_kernel<<<dim3(D_MODEL / 32, D_INNER / 32), 256, 0, stream>>>(W_out, wtmp, D_INNER, D_MODEL);

    // 10) out_proj GEMM (bf16 MFMA) + bias + residual
    gemm_mfma<2><<<dim3(D_MODEL / 128, BL / 128), 256, 0, stream>>>(
        ybf, wtmp, b_out, x, zbuf, nullptr, BL, D_MODEL, D_INNER);

    // 11) LayerNorm
    layernorm_kernel<<<BL, 256, 0, stream>>>(zbuf, ln_g, ln_b, out);
}

// Round 5
// 403.361 us; speedup vs baseline: 4.9650x; 1.0407x over previous
//
#include <hip/hip_runtime.h>
#include <math.h>

#define D_MODEL 1024
#define D_INNER 2048
#define D_STATE 16
#define D_CONV  4
#define NCHUNK  8
#define LCHUNK  128

typedef unsigned short u16;
typedef __attribute__((ext_vector_type(8))) short short8;
typedef __attribute__((ext_vector_type(4))) float f32x4;
typedef __attribute__((ext_vector_type(4))) unsigned short u16x4;

__device__ __forceinline__ float silu_f(float x) { return x / (1.f + __expf(-x)); }
__device__ __forceinline__ float softplus_f(float x) {
    return fmaxf(x, 0.f) + log1pf(__expf(-fabsf(x)));
}
__device__ __forceinline__ u16 f2bf(float f) {
    union { float f; unsigned u; } c; c.f = f;
    unsigned r = c.u + 0x7fffu + ((c.u >> 16) & 1u);   // RNE
    return (u16)(r >> 16);
}
__device__ __forceinline__ void gload_lds16(const void* g, void* l) {
    __builtin_amdgcn_global_load_lds((const __attribute__((address_space(1))) void*)g,
                                     (__attribute__((address_space(3))) void*)l, 16, 0, 0);
}

// ---------------------------------------------------------------------------
// fp32 -> bf16 elementwise convert (4 elems/thread)
// ---------------------------------------------------------------------------
__global__ __launch_bounds__(256)
void f32_to_bf16_kernel(const float* __restrict__ in, u16* __restrict__ out, int n4)
{
    const int i = blockIdx.x * 256 + threadIdx.x;
    if (i >= n4) return;
    const float4 v = *(const float4*)&in[(size_t)i * 4];
    u16x4 o; o.x = f2bf(v.x); o.y = f2bf(v.y); o.z = f2bf(v.z); o.w = f2bf(v.w);
    *(u16x4*)&out[(size_t)i * 4] = o;
}

// ---------------------------------------------------------------------------
// W[K][N] fp32 -> Wt[N][K] bf16 (32x32 LDS tiles)
// ---------------------------------------------------------------------------
__global__ __launch_bounds__(256)
void transpose_bf16_kernel(const float* __restrict__ W, u16* __restrict__ Wt, int K, int N)
{
    __shared__ float tile[32][33];
    const int tx = threadIdx.x & 31, ty = threadIdx.x >> 5;
    const int n0 = blockIdx.x * 32, k0 = blockIdx.y * 32;
#pragma unroll
    for (int q = 0; q < 4; q++)
        tile[ty + q * 8][tx] = W[(size_t)(k0 + ty + q * 8) * N + n0 + tx];
    __syncthreads();
#pragma unroll
    for (int q = 0; q < 4; q++)
        Wt[(size_t)(n0 + ty + q * 8) * K + k0 + tx] = f2bf(tile[tx][ty + q * 8]);
}

// ---------------------------------------------------------------------------
// bf16 MFMA GEMM: C(MxN) = A(MxK) * Bt(NxK)^T + bias, fused epilogues (fp32 out).
// 128x128 tile, BK=32, 256 threads = 4 waves, each wave 64x64 (4x4 frags 16x16x32).
// Double-buffered LDS + counted vmcnt(4) + raw s_barrier (T3-min/T4).
// LDS slot swizzle: slot' = kg ^ ((row>>1)&3), applied via pre-swizzled global
// source (LDS dest linear, rule 21) + swizzled ds_read address.
// ---------------------------------------------------------------------------
template <int MODE>
__global__ __launch_bounds__(256)
void gemm_mfma(const u16* __restrict__ A, const u16* __restrict__ Bt,
               const float* __restrict__ bias, const float* __restrict__ aux,
               float* __restrict__ out0, float* __restrict__ out1,
               int M, int N, int K)
{
    __shared__ __align__(16) short As[2][4096];
    __shared__ __align__(16) short Bs[2][4096];

    const int tid = threadIdx.x;
    const int wid = tid >> 6, lane = tid & 63;
    const int wr = wid >> 1, wc = wid & 1;
    const int row0 = blockIdx.y * 128, col0 = blockIdx.x * 128;

    f32x4 acc[4][4] = {};

    const int c0 = wid * 128 + lane;   // staging chunk ids (16B each)
    const int c1 = c0 + 64;
    const u16* Abase = A + (size_t)row0 * K;
    const u16* Bbase = Bt + (size_t)col0 * K;

    // pre-swizzled global k-offset (elements): gslot = (lane&3) ^ ((lane>>3)&3)
    const int gsl8 = (((lane & 3) ^ ((lane >> 3) & 3)) << 3);

    const int kg = lane >> 4, r16 = lane & 15;
    const int sl8 = ((kg ^ ((r16 >> 1) & 3)) << 3);   // swizzled read slot (elements)

#define STAGE(bi, kk) do {                                                          \
        gload_lds16(Abase + (size_t)(c0 >> 2) * K + (kk) + gsl8, &As[bi][wid * 1024]);       \
        gload_lds16(Abase + (size_t)(c1 >> 2) * K + (kk) + gsl8, &As[bi][wid * 1024 + 512]); \
        gload_lds16(Bbase + (size_t)(c0 >> 2) * K + (kk) + gsl8, &Bs[bi][wid * 1024]);       \
        gload_lds16(Bbase + (size_t)(c1 >> 2) * K + (kk) + gsl8, &Bs[bi][wid * 1024 + 512]); \
    } while (0)

    const int nt = K >> 5;
    STAGE(0, 0);
    int cur = 0;
    for (int t = 0; t < nt; ++t) {
        if (t + 1 < nt) {
            STAGE(cur ^ 1, (t + 1) << 5);
            asm volatile("s_waitcnt vmcnt(4)" ::: "memory");   // tile t's 4 loads done
        } else {
            asm volatile("s_waitcnt vmcnt(0)" ::: "memory");
        }
        __builtin_amdgcn_s_barrier();

        short8 af[4], bg[4];
#pragma unroll
        for (int i = 0; i < 4; i++) {
            const int r = wr * 64 + i * 16 + r16;
            af[i] = *(const short8*)&As[cur][r * 32 + sl8];
        }
#pragma unroll
        for (int j = 0; j < 4; j++) {
            const int r = wc * 64 + j * 16 + r16;
            bg[j] = *(const short8*)&Bs[cur][r * 32 + sl8];
        }
#pragma unroll
        for (int i = 0; i < 4; i++)
#pragma unroll
            for (int j = 0; j < 4; j++)
                acc[i][j] = __builtin_amdgcn_mfma_f32_16x16x32_bf16(af[i], bg[j], acc[i][j], 0, 0, 0);

        asm volatile("s_waitcnt lgkmcnt(0)" ::: "memory");     // reads retired before overwrite
        __builtin_amdgcn_s_barrier();
        cur ^= 1;
    }
#undef STAGE

    // epilogue: D layout col = lane&15, row = (lane>>4)*4 + reg
#pragma unroll
    for (int i = 0; i < 4; i++) {
#pragma unroll
        for (int j = 0; j < 4; j++) {
#pragma unroll
            for (int r = 0; r < 4; r++) {
                const int row = row0 + wr * 64 + i * 16 + kg * 4 + r;
                const int col = col0 + wc * 64 + j * 16 + r16;
                float v = acc[i][j][r] + bias[col];
                if (MODE == 0) {
                    if (col < D_INNER) out0[(size_t)row * D_INNER + col] = silu_f(v);
                    else               out1[(size_t)row * D_INNER + (col - D_INNER)] = v;
                } else if (MODE == 1) {
                    out0[(size_t)row * N + col] = softplus_f(v);
                } else {
                    out0[(size_t)row * N + col] = v + aux[(size_t)row * N + col];
                }
            }
        }
    }
}

// ---------------------------------------------------------------------------
// Depthwise causal conv1d (+bias) + silu. Writes fp32 and bf16 copies.
// ---------------------------------------------------------------------------
__global__ __launch_bounds__(256)
void conv_silu_kernel(const float* __restrict__ xi, const float* __restrict__ w,
                      const float* __restrict__ cb, float* __restrict__ xc,
                      u16* __restrict__ xcb, int total)
{
    const int i = blockIdx.x * 256 + threadIdx.x;
    if (i >= total) return;
    const int d = i & (D_INNER - 1);
    const int bl = i >> 11;
    const int l = bl & 1023;
    float acc = cb[d];
#pragma unroll
    for (int k = 0; k < D_CONV; k++) {
        const int li = l + k - (D_CONV - 1);
        if (li >= 0) acc = fmaf(w[d * D_CONV + k], xi[(size_t)i + (k - (D_CONV - 1)) * D_INNER], acc);
    }
    const float s = silu_f(acc);
    xc[i] = s;
    xcb[i] = f2bf(s);
}

// ---------------------------------------------------------------------------
// x_proj: bc(BL x 32) = xc(BL x 2048) @ W_xp(2048 x 32) + b_xp   (fp32)
// ---------------------------------------------------------------------------
__global__ __launch_bounds__(128)
void xproj_kernel(const float* __restrict__ xc, const float* __restrict__ W,
                  const float* __restrict__ bxp, float* __restrict__ bc)
{
    const int row = blockIdx.x;
    const int c = threadIdx.x & 31, s = threadIdx.x >> 5;
    const float* xr = xc + (size_t)row * D_INNER;
    float acc = 0.f;
    for (int k = s * 512; k < (s + 1) * 512; k += 4) {
        const float4 xv = *(const float4*)&xr[k];
        acc = fmaf(xv.x, W[(k + 0) * 32 + c], acc);
        acc = fmaf(xv.y, W[(k + 1) * 32 + c], acc);
        acc = fmaf(xv.z, W[(k + 2) * 32 + c], acc);
        acc = fmaf(xv.w, W[(k + 3) * 32 + c], acc);
    }
    __shared__ float red[4][32];
    red[s][c] = acc;
    __syncthreads();
    if (s == 0)
        bc[(size_t)row * 32 + c] = red[0][c] + red[1][c] + red[2][c] + red[3][c] + bxp[c];
}

// ---------------------------------------------------------------------------
// SSM scan phase 1: per (b, d, n, chunk) chunk-local end state + dt-sum.
// ---------------------------------------------------------------------------
__global__ __launch_bounds__(256)
void ssm_s1_kernel(const float* __restrict__ xc, const float* __restrict__ dt,
                   const float* __restrict__ bc, const float* __restrict__ A_log,
                   float* __restrict__ hend, float* __restrict__ dtsum)
{
    const int tid = threadIdx.x;
    const int ch = tid >> 4, n = tid & 15;
    const int d0 = blockIdx.x * 16;
    const int c = blockIdx.y;
    const int b = blockIdx.z;
    const int d = d0 + ch;

    const float Aln = -__expf(A_log[d * D_STATE + n]);

    __shared__ float sdt[64][16], sdtx[64][16], sB[64][16];

    float h = 0.f, S = 0.f;

    for (int half = 0; half < 2; half++) {
        const int l0 = c * LCHUNK + half * 64;
        __syncthreads();
        {
            const int l = tid >> 2, di = (tid & 3) << 2;
            const size_t g = ((size_t)(b * 1024 + l0 + l)) * D_INNER + d0 + di;
            const float4 dv = *(const float4*)&dt[g];
            const float4 xv = *(const float4*)&xc[g];
            float4 dx;
            dx.x = dv.x * xv.x; dx.y = dv.y * xv.y; dx.z = dv.z * xv.z; dx.w = dv.w * xv.w;
            *(float4*)&sdt[l][di] = dv;
            *(float4*)&sdtx[l][di] = dx;
            *(float4*)&sB[l][di] = *(const float4*)&bc[((size_t)(b * 1024 + l0 + l)) * 32 + di];
        }
        __syncthreads();
#pragma unroll 16
        for (int l = 0; l < 64; l++) {
            const float dtv = sdt[l][ch];
            const float a = __expf(dtv * Aln);
            h = fmaf(a, h, sdtx[l][ch] * sB[l][n]);
            S += dtv;
        }
    }
    hend[((size_t)(b * NCHUNK + c) * D_INNER + d) * D_STATE + n] = h;
    if (n == 0) dtsum[(size_t)(b * NCHUNK + c) * D_INNER + d] = S;
}

// ---------------------------------------------------------------------------
// SSM scan phase 3: combine h_in, rerun recurrence, emit y (bf16).
// ---------------------------------------------------------------------------
__global__ __launch_bounds__(256)
void ssm_s3_kernel(const float* __restrict__ xc, const float* __restrict__ dt,
                   const float* __restrict__ bc, const float* __restrict__ A_log,
                   const float* __restrict__ Dp, const float* __restrict__ res,
                   const float* __restrict__ hend, const float* __restrict__ dtsum,
                   u16* __restrict__ ybf)
{
    const int tid = threadIdx.x;
    const int wid = tid >> 6, lane = tid & 63;
    const int ch4 = lane >> 4, n = lane & 15;
    const int ch = wid * 4 + ch4;
    const int d0 = blockIdx.x * 16;
    const int c = blockIdx.y;
    const int b = blockIdx.z;
    const int d = d0 + ch;

    const float Aln = -__expf(A_log[d * D_STATE + n]);
    const float Dv = Dp[d];

    float h = 0.f;
    for (int cc = 0; cc < c; cc++) {
        const float S = dtsum[(size_t)(b * NCHUNK + cc) * D_INNER + d];
        const float P = __expf(Aln * S);
        h = fmaf(P, h, hend[((size_t)(b * NCHUNK + cc) * D_INNER + d) * D_STATE + n]);
    }

    __shared__ float sdt[64][16], sdtx[64][16], sx[64][16], sres[64][16];
    __shared__ float sbc[64][32];
    __shared__ float pbuf[4 * 16 * 68];

    float* pw = &pbuf[wid * 16 * 68];

    for (int half = 0; half < 2; half++) {
        const int l0 = c * LCHUNK + half * 64;
        __syncthreads();
        {
            const int l = tid >> 2, di = (tid & 3) << 2;
            const size_t g = ((size_t)(b * 1024 + l0 + l)) * D_INNER + d0 + di;
            const float4 dv = *(const float4*)&dt[g];
            const float4 xv = *(const float4*)&xc[g];
            const float4 rv = *(const float4*)&res[g];
            float4 dx;
            dx.x = dv.x * xv.x; dx.y = dv.y * xv.y; dx.z = dv.z * xv.z; dx.w = dv.w * xv.w;
            *(float4*)&sdt[l][di] = dv;
            *(float4*)&sdtx[l][di] = dx;
            *(float4*)&sx[l][di] = xv;
            *(float4*)&sres[l][di] = rv;
            const int r0 = tid >> 3, c4 = (tid & 7) << 2;
            *(float4*)&sbc[r0][c4] = *(const float4*)&bc[((size_t)(b * 1024 + l0 + r0)) * 32 + c4];
            const int r1 = (tid + 256) >> 3;
            *(float4*)&sbc[r1][c4] = *(const float4*)&bc[((size_t)(b * 1024 + l0 + r1)) * 32 + c4];
        }
        __syncthreads();

        for (int l16 = 0; l16 < 4; l16++) {
#pragma unroll
            for (int j = 0; j < 16; j++) {
                const int l = l16 * 16 + j;
                const float dtv = sdt[l][ch];
                const float a = __expf(dtv * Aln);
                h = fmaf(a, h, sdtx[l][ch] * sbc[l][n]);
                pw[j * 68 + ch4 * 16 + n] = h * sbc[l][16 + n];
            }
            __builtin_amdgcn_wave_barrier();
            const float4 q0 = *(const float4*)&pw[n * 68 + ch4 * 16 + 0];
            const float4 q1 = *(const float4*)&pw[n * 68 + ch4 * 16 + 4];
            const float4 q2 = *(const float4*)&pw[n * 68 + ch4 * 16 + 8];
            const float4 q3 = *(const float4*)&pw[n * 68 + ch4 * 16 + 12];
            const float sum = ((q0.x + q0.y) + (q0.z + q0.w)) + ((q1.x + q1.y) + (q1.z + q1.w))
                            + ((q2.x + q2.y) + (q2.z + q2.w)) + ((q3.x + q3.y) + (q3.z + q3.w));
            const int t = l16 * 16 + n;
            const float xv = sx[t][ch];
            const float rv = sres[t][ch];
            const float yv = (sum + xv * Dv) * silu_f(rv);
            ybf[((size_t)(b * 1024 + l0 + t)) * D_INNER + d] = f2bf(yv);
            __builtin_amdgcn_wave_barrier();
        }
    }
}

// ---------------------------------------------------------------------------
// LayerNorm over D_MODEL=1024 per row.
// ---------------------------------------------------------------------------
__global__ __launch_bounds__(256)
void layernorm_kernel(const float* __restrict__ z, const float* __restrict__ g,
                      const float* __restrict__ beta, float* __restrict__ out)
{
    const int row = blockIdx.x;
    const int tid = threadIdx.x;
    const float* zr = z + (size_t)row * D_MODEL;
    const float4 v = *(const float4*)&zr[tid << 2];
    float s = v.x + v.y + v.z + v.w;
    float ss = v.x * v.x + v.y * v.y + v.z * v.z + v.w * v.w;

    __shared__ float sm[256], sq[256];
    sm[tid] = s; sq[tid] = ss;
    __syncthreads();
    for (int off = 128; off > 0; off >>= 1) {
        if (tid < off) { sm[tid] += sm[tid + off]; sq[tid] += sq[tid + off]; }
        __syncthreads();
    }
    const float mean = sm[0] * (1.f / D_MODEL);
    const float var = sq[0] * (1.f / D_MODEL) - mean * mean;
    const float rstd = rsqrtf(var + 1e-5f);

    float4 o;
    o.x = (v.x - mean) * rstd * g[(tid << 2) + 0] + beta[(tid << 2) + 0];
    o.y = (v.y - mean) * rstd * g[(tid << 2) + 1] + beta[(tid << 2) + 1];
    o.z = (v.z - mean) * rstd * g[(tid << 2) + 2] + beta[(tid << 2) + 2];
    o.w = (v.w - mean) * rstd * g[(tid << 2) + 3] + beta[(tid << 2) + 3];
    *(float4*)&out[(size_t)row * D_MODEL + (tid << 2)] = o;
}

// ---------------------------------------------------------------------------
extern "C" void kernel_launch(void* const* d_in, const int* in_sizes, int n_in,
                              void* d_out, int out_size, void* d_ws, size_t ws_size,
                              hipStream_t stream)
{
    const float* x      = (const float*)d_in[0];
    const float* W_in   = (const float*)d_in[1];
    const float* b_in   = (const float*)d_in[2];
    const float* conv_w = (const float*)d_in[3];
    const float* conv_b = (const float*)d_in[4];
    const float* W_xp   = (const float*)d_in[5];
    const float* b_xp   = (const float*)d_in[6];
    const float* W_dt   = (const float*)d_in[7];
    const float* b_dt   = (const float*)d_in[8];
    const float* A_log  = (const float*)d_in[9];
    const float* D_par  = (const float*)d_in[10];
    const float* W_out  = (const float*)d_in[11];
    const float* b_out  = (const float*)d_in[12];
    const float* ln_g   = (const float*)d_in[13];
    const float* ln_b   = (const float*)d_in[14];
    float* out = (float*)d_out;

    const int BL = in_sizes[0] / D_MODEL;   // 4096
    const int Bb = BL / 1024;               // 4
    const size_t BLD = (size_t)BL * D_INNER;

    // workspace layout
    float* ws = (float*)d_ws;
    float* xi_act = ws;                     // BLD f32 ; later reused (as u16) by ybf
    float* resb   = ws + BLD;               // BLD f32
    float* xcb    = ws + 2 * BLD;           // BLD f32
    float* dtb    = ws + 3 * BLD;           // BLD f32 ; later zbuf
    float* bcbuf  = ws + 4 * BLD;           // BL*32 f32
    u16*   xbf    = (u16*)(ws + 4 * BLD + (size_t)BL * 32);  // BL*1024 u16
    u16*   xcbf   = xbf + (size_t)BL * D_MODEL;              // BLD u16
    u16*   wtmp   = xcbf + BLD;                              // up to 4M u16
    float* hend   = (float*)(wtmp + (size_t)4 * 1024 * 1024); // B*NCHUNK*D_INNER*16
    float* dtsum  = hend + (size_t)Bb * NCHUNK * D_INNER * D_STATE; // B*NCHUNK*D_INNER
    u16*   ybf    = (u16*)xi_act;
    float* zbuf   = dtb;

    // 1) x -> bf16
    f32_to_bf16_kernel<<<(BL * D_MODEL / 4 + 255) / 256, 256, 0, stream>>>(x, xbf, BL * D_MODEL / 4);

    // 2) W_in (1024x4096) -> Wt bf16 (4096x1024)
    transpose_bf16_kernel<<<dim3(2 * D_INNER / 32, D_MODEL / 32), 256, 0, stream>>>(W_in, wtmp, D_MODEL, 2 * D_INNER);

    // 3) in_proj GEMM (bf16 MFMA): silu-half + gate-half
    gemm_mfma<0><<<dim3(2 * D_INNER / 128, BL / 128), 256, 0, stream>>>(
        xbf, wtmp, b_in, nullptr, xi_act, resb, BL, 2 * D_INNER, D_MODEL);

    // 4) depthwise causal conv + silu (fp32 + bf16 outputs)
    conv_silu_kernel<<<(int)(BLD / 256), 256, 0, stream>>>(
        xi_act, conv_w, conv_b, xcb, xcbf, (int)BLD);

    // 5) x_proj -> B,C (fp32)
    xproj_kernel<<<BL, 128, 0, stream>>>(xcb, W_xp, b_xp, bcbuf);

    // 6) W_dt (2048x2048) -> Wt bf16
    transpose_bf16_kernel<<<dim3(D_INNER / 32, D_INNER / 32), 256, 0, stream>>>(W_dt, wtmp, D_INNER, D_INNER);

    // 7) dt_proj GEMM (bf16 MFMA) + softplus
    gemm_mfma<1><<<dim3(D_INNER / 128, BL / 128), 256, 0, stream>>>(
        xcbf, wtmp, b_dt, nullptr, dtb, nullptr, BL, D_INNER, D_INNER);

    // 8a) scan phase 1: chunk-local end states + dt sums
    ssm_s1_kernel<<<dim3(D_INNER / 16, NCHUNK, Bb), 256, 0, stream>>>(
        xcb, dtb, bcbuf, A_log, hend, dtsum);

    // 8b) scan phase 3: combine + rerun + emit y (bf16)
    ssm_s3_kernel<<<dim3(D_INNER / 16, NCHUNK, Bb), 256, 0, stream>>>(
        xcb, dtb, bcbuf, A_log, D_par, resb, hend, dtsum, ybf);

    // 9) W_out (2048x1024) -> Wt bf16
    transpose_bf16_kernel<<<dim3(D_MODEL / 32, D_INNER / 32), 256, 0, stream>>>(W_out, wtmp, D_INNER, D_MODEL);

    // 10) out_proj GEMM (bf16 MFMA) + bias + residual
    gemm_mfma<2><<<dim3(D_MODEL / 128, BL / 128), 256, 0, stream>>>(
        ybf, wtmp, b_out, x, zbuf, nullptr, BL, D_MODEL, D_INNER);

    // 11) LayerNorm
    layernorm_kernel<<<BL, 256, 0, stream>>>(zbuf, ln_g, ln_b, out);
}

// Round 6
// 368.178 us; speedup vs baseline: 5.4394x; 1.0956x over previous
//
#include <hip/hip_runtime.h>
#include <math.h>

#define D_MODEL 1024
#define D_INNER 2048
#define D_STATE 16
#define D_CONV  4
#define NCHUNK  8
#define LCHUNK  128

typedef unsigned short u16;
typedef __attribute__((ext_vector_type(8))) short short8;
typedef __attribute__((ext_vector_type(4))) float f32x4;
typedef __attribute__((ext_vector_type(4))) unsigned short u16x4;

__device__ __forceinline__ float silu_f(float x) { return x / (1.f + __expf(-x)); }
__device__ __forceinline__ float softplus_f(float x) {
    return fmaxf(x, 0.f) + log1pf(__expf(-fabsf(x)));
}
__device__ __forceinline__ u16 f2bf(float f) {
    union { float f; unsigned u; } c; c.f = f;
    unsigned r = c.u + 0x7fffu + ((c.u >> 16) & 1u);   // RNE
    return (u16)(r >> 16);
}
__device__ __forceinline__ float bf2f(u16 v) {
    union { unsigned u; float f; } c; c.u = ((unsigned)v) << 16; return c.f;
}
__device__ __forceinline__ void gload_lds16(const void* g, void* l) {
    __builtin_amdgcn_global_load_lds((const __attribute__((address_space(1))) void*)g,
                                     (__attribute__((address_space(3))) void*)l, 16, 0, 0);
}

// ---------------------------------------------------------------------------
// fp32 -> bf16 elementwise convert (4 elems/thread)
// ---------------------------------------------------------------------------
__global__ __launch_bounds__(256)
void f32_to_bf16_kernel(const float* __restrict__ in, u16* __restrict__ out, int n4)
{
    const int i = blockIdx.x * 256 + threadIdx.x;
    if (i >= n4) return;
    const float4 v = *(const float4*)&in[(size_t)i * 4];
    u16x4 o; o.x = f2bf(v.x); o.y = f2bf(v.y); o.z = f2bf(v.z); o.w = f2bf(v.w);
    *(u16x4*)&out[(size_t)i * 4] = o;
}

// ---------------------------------------------------------------------------
// W[K][N] fp32 -> Wt[N][K] bf16 (32x32 LDS tiles)
// ---------------------------------------------------------------------------
__global__ __launch_bounds__(256)
void transpose_bf16_kernel(const float* __restrict__ W, u16* __restrict__ Wt, int K, int N)
{
    __shared__ float tile[32][33];
    const int tx = threadIdx.x & 31, ty = threadIdx.x >> 5;
    const int n0 = blockIdx.x * 32, k0 = blockIdx.y * 32;
#pragma unroll
    for (int q = 0; q < 4; q++)
        tile[ty + q * 8][tx] = W[(size_t)(k0 + ty + q * 8) * N + n0 + tx];
    __syncthreads();
#pragma unroll
    for (int q = 0; q < 4; q++)
        Wt[(size_t)(n0 + ty + q * 8) * K + k0 + tx] = f2bf(tile[tx][ty + q * 8]);
}

// ---------------------------------------------------------------------------
// bf16 MFMA GEMM: C(MxN) = A(MxK) * Bt(NxK)^T + bias, fused epilogues.
// 128x128 tile, BK=32, 4 waves, 4x4 frags of 16x16x32 per wave.
// Triple-buffered LDS, depth-2 prefetch, counted vmcnt(8), setprio MFMA.
// LDS slot swizzle both-sides (pre-swizzled global source, swizzled read).
// MODE 0: col<D_INNER -> out0(u16)=bf16(silu(v)); else out1(u16)=bf16(v)
// MODE 1: out0(f32) = softplus(v)
// MODE 2: out0(f32) = v + aux[row*N+col]
// ---------------------------------------------------------------------------
template <int MODE>
__global__ __launch_bounds__(256)
void gemm_mfma(const u16* __restrict__ A, const u16* __restrict__ Bt,
               const float* __restrict__ bias, const float* __restrict__ aux,
               void* __restrict__ out0v, void* __restrict__ out1v,
               int M, int N, int K)
{
    __shared__ __align__(16) short As[3][4096];
    __shared__ __align__(16) short Bs[3][4096];

    const int tid = threadIdx.x;
    const int wid = tid >> 6, lane = tid & 63;
    const int wr = wid >> 1, wc = wid & 1;
    const int row0 = blockIdx.y * 128, col0 = blockIdx.x * 128;

    f32x4 acc[4][4] = {};

    const int c0 = wid * 128 + lane;   // staging chunk ids (16B each)
    const int c1 = c0 + 64;
    const u16* Abase = A + (size_t)row0 * K;
    const u16* Bbase = Bt + (size_t)col0 * K;

    // pre-swizzled global k-offset: gslot = (lane&3) ^ ((lane>>3)&3)
    const int gsl8 = (((lane & 3) ^ ((lane >> 3) & 3)) << 3);

    const int kg = lane >> 4, r16 = lane & 15;
    const int sl8 = ((kg ^ ((r16 >> 1) & 3)) << 3);   // swizzled read slot

#define STAGE(bi, kk) do {                                                                   \
        gload_lds16(Abase + (size_t)(c0 >> 2) * K + (kk) + gsl8, &As[bi][wid * 1024]);       \
        gload_lds16(Abase + (size_t)(c1 >> 2) * K + (kk) + gsl8, &As[bi][wid * 1024 + 512]); \
        gload_lds16(Bbase + (size_t)(c0 >> 2) * K + (kk) + gsl8, &Bs[bi][wid * 1024]);       \
        gload_lds16(Bbase + (size_t)(c1 >> 2) * K + (kk) + gsl8, &Bs[bi][wid * 1024 + 512]); \
    } while (0)

    const int nt = K >> 5;
    STAGE(0, 0);
    STAGE(1, 32);
    int cs = 0;   // compute slot = t % 3
    for (int t = 0; t < nt; ++t) {
        if (t + 2 < nt) {
            const int ss = (cs + 2 >= 3) ? cs - 1 : cs + 2;   // (t+2)%3
            STAGE(ss, (t + 2) << 5);
            asm volatile("s_waitcnt vmcnt(8)" ::: "memory");   // tile t done
        } else if (t + 1 < nt) {
            asm volatile("s_waitcnt vmcnt(4)" ::: "memory");
        } else {
            asm volatile("s_waitcnt vmcnt(0)" ::: "memory");
        }
        __builtin_amdgcn_s_barrier();

        short8 af[4], bg[4];
#pragma unroll
        for (int i = 0; i < 4; i++) {
            const int r = wr * 64 + i * 16 + r16;
            af[i] = *(const short8*)&As[cs][r * 32 + sl8];
        }
#pragma unroll
        for (int j = 0; j < 4; j++) {
            const int r = wc * 64 + j * 16 + r16;
            bg[j] = *(const short8*)&Bs[cs][r * 32 + sl8];
        }
        __builtin_amdgcn_s_setprio(1);
#pragma unroll
        for (int i = 0; i < 4; i++)
#pragma unroll
            for (int j = 0; j < 4; j++)
                acc[i][j] = __builtin_amdgcn_mfma_f32_16x16x32_bf16(af[i], bg[j], acc[i][j], 0, 0, 0);
        __builtin_amdgcn_s_setprio(0);

        asm volatile("s_waitcnt lgkmcnt(0)" ::: "memory");     // reads retired before overwrite
        __builtin_amdgcn_s_barrier();
        cs = (cs + 1 >= 3) ? 0 : cs + 1;
    }
#undef STAGE

    // epilogue: D layout col = lane&15, row = (lane>>4)*4 + reg
#pragma unroll
    for (int i = 0; i < 4; i++) {
#pragma unroll
        for (int j = 0; j < 4; j++) {
#pragma unroll
            for (int r = 0; r < 4; r++) {
                const int row = row0 + wr * 64 + i * 16 + kg * 4 + r;
                const int col = col0 + wc * 64 + j * 16 + r16;
                float v = acc[i][j][r] + bias[col];
                if (MODE == 0) {
                    u16* o0 = (u16*)out0v; u16* o1 = (u16*)out1v;
                    if (col < D_INNER) o0[(size_t)row * D_INNER + col] = f2bf(silu_f(v));
                    else               o1[(size_t)row * D_INNER + (col - D_INNER)] = f2bf(v);
                } else if (MODE == 1) {
                    ((float*)out0v)[(size_t)row * N + col] = softplus_f(v);
                } else {
                    ((float*)out0v)[(size_t)row * N + col] = v + aux[(size_t)row * N + col];
                }
            }
        }
    }
}

// ---------------------------------------------------------------------------
// Depthwise causal conv1d (+bias) + silu. Reads bf16 xi; writes f32 + bf16.
// ---------------------------------------------------------------------------
__global__ __launch_bounds__(256)
void conv_silu_kernel(const u16* __restrict__ xi, const float* __restrict__ w,
                      const float* __restrict__ cb, float* __restrict__ xc,
                      u16* __restrict__ xcb, int total)
{
    const int i = blockIdx.x * 256 + threadIdx.x;
    if (i >= total) return;
    const int d = i & (D_INNER - 1);
    const int l = (i >> 11) & 1023;
    float acc = cb[d];
#pragma unroll
    for (int k = 0; k < D_CONV; k++) {
        const int li = l + k - (D_CONV - 1);
        if (li >= 0) acc = fmaf(w[d * D_CONV + k], bf2f(xi[(size_t)i + (k - (D_CONV - 1)) * D_INNER]), acc);
    }
    const float s = silu_f(acc);
    xc[i] = s;
    xcb[i] = f2bf(s);
}

// ---------------------------------------------------------------------------
// x_proj as tiny MFMA GEMM: bc(BL x 32) = xcbf(BL x 2048) @ WxpT(32 x 2048)^T
// No LDS: A/B read straight from global (L2-hot). 4 waves/block, 16 tokens/wave.
// ---------------------------------------------------------------------------
__global__ __launch_bounds__(256)
void xproj_mfma_kernel(const u16* __restrict__ A, const u16* __restrict__ Wt,
                       const float* __restrict__ bxp, float* __restrict__ bc)
{
    const int wid = threadIdx.x >> 6, lane = threadIdx.x & 63;
    const int kg = lane >> 4, r16 = lane & 15;
    const int tok0 = blockIdx.x * 64 + wid * 16;

    f32x4 acc[2] = {};
#pragma unroll 4
    for (int k0 = 0; k0 < D_INNER; k0 += 32) {
        const short8 a  = *(const short8*)&A[(size_t)(tok0 + r16) * D_INNER + k0 + kg * 8];
        const short8 b0 = *(const short8*)&Wt[(size_t)r16 * D_INNER + k0 + kg * 8];
        const short8 b1 = *(const short8*)&Wt[(size_t)(16 + r16) * D_INNER + k0 + kg * 8];
        acc[0] = __builtin_amdgcn_mfma_f32_16x16x32_bf16(a, b0, acc[0], 0, 0, 0);
        acc[1] = __builtin_amdgcn_mfma_f32_16x16x32_bf16(a, b1, acc[1], 0, 0, 0);
    }
#pragma unroll
    for (int j = 0; j < 2; j++)
#pragma unroll
        for (int r = 0; r < 4; r++) {
            const int token = tok0 + kg * 4 + r;
            const int c = j * 16 + r16;
            bc[(size_t)token * 32 + c] = acc[j][r] + bxp[c];
        }
}

// ---------------------------------------------------------------------------
// SSM scan phase 1: per (b, d, n, chunk) chunk-local end state + dt-sum.
// ---------------------------------------------------------------------------
__global__ __launch_bounds__(256)
void ssm_s1_kernel(const float* __restrict__ xc, const float* __restrict__ dt,
                   const float* __restrict__ bc, const float* __restrict__ A_log,
                   float* __restrict__ hend, float* __restrict__ dtsum)
{
    const int tid = threadIdx.x;
    const int ch = tid >> 4, n = tid & 15;
    const int d0 = blockIdx.x * 16;
    const int c = blockIdx.y;
    const int b = blockIdx.z;
    const int d = d0 + ch;

    const float Aln = -__expf(A_log[d * D_STATE + n]);

    __shared__ float sdt[64][16], sdtx[64][16], sB[64][16];

    float h = 0.f, S = 0.f;

    for (int half = 0; half < 2; half++) {
        const int l0 = c * LCHUNK + half * 64;
        __syncthreads();
        {
            const int l = tid >> 2, di = (tid & 3) << 2;
            const size_t g = ((size_t)(b * 1024 + l0 + l)) * D_INNER + d0 + di;
            const float4 dv = *(const float4*)&dt[g];
            const float4 xv = *(const float4*)&xc[g];
            float4 dx;
            dx.x = dv.x * xv.x; dx.y = dv.y * xv.y; dx.z = dv.z * xv.z; dx.w = dv.w * xv.w;
            *(float4*)&sdt[l][di] = dv;
            *(float4*)&sdtx[l][di] = dx;
            *(float4*)&sB[l][di] = *(const float4*)&bc[((size_t)(b * 1024 + l0 + l)) * 32 + di];
        }
        __syncthreads();
#pragma unroll 16
        for (int l = 0; l < 64; l++) {
            const float dtv = sdt[l][ch];
            const float a = __expf(dtv * Aln);
            h = fmaf(a, h, sdtx[l][ch] * sB[l][n]);
            S += dtv;
        }
    }
    hend[((size_t)(b * NCHUNK + c) * D_INNER + d) * D_STATE + n] = h;
    if (n == 0) dtsum[(size_t)(b * NCHUNK + c) * D_INNER + d] = S;
}

// ---------------------------------------------------------------------------
// SSM scan phase 3: combine h_in, rerun recurrence, emit y (bf16).
// res is bf16 now.
// ---------------------------------------------------------------------------
__global__ __launch_bounds__(256)
void ssm_s3_kernel(const float* __restrict__ xc, const float* __restrict__ dt,
                   const float* __restrict__ bc, const float* __restrict__ A_log,
                   const float* __restrict__ Dp, const u16* __restrict__ resbf,
                   const float* __restrict__ hend, const float* __restrict__ dtsum,
                   u16* __restrict__ ybf)
{
    const int tid = threadIdx.x;
    const int wid = tid >> 6, lane = tid & 63;
    const int ch4 = lane >> 4, n = lane & 15;
    const int ch = wid * 4 + ch4;
    const int d0 = blockIdx.x * 16;
    const int c = blockIdx.y;
    const int b = blockIdx.z;
    const int d = d0 + ch;

    const float Aln = -__expf(A_log[d * D_STATE + n]);
    const float Dv = Dp[d];

    float h = 0.f;
    for (int cc = 0; cc < c; cc++) {
        const float S = dtsum[(size_t)(b * NCHUNK + cc) * D_INNER + d];
        const float P = __expf(Aln * S);
        h = fmaf(P, h, hend[((size_t)(b * NCHUNK + cc) * D_INNER + d) * D_STATE + n]);
    }

    __shared__ float sdt[64][16], sdtx[64][16], sx[64][16], sres[64][16];
    __shared__ float sbc[64][32];
    __shared__ float pbuf[4 * 16 * 68];

    float* pw = &pbuf[wid * 16 * 68];

    for (int half = 0; half < 2; half++) {
        const int l0 = c * LCHUNK + half * 64;
        __syncthreads();
        {
            const int l = tid >> 2, di = (tid & 3) << 2;
            const size_t g = ((size_t)(b * 1024 + l0 + l)) * D_INNER + d0 + di;
            const float4 dv = *(const float4*)&dt[g];
            const float4 xv = *(const float4*)&xc[g];
            const u16x4 rv = *(const u16x4*)&resbf[g];
            float4 dx;
            dx.x = dv.x * xv.x; dx.y = dv.y * xv.y; dx.z = dv.z * xv.z; dx.w = dv.w * xv.w;
            *(float4*)&sdt[l][di] = dv;
            *(float4*)&sdtx[l][di] = dx;
            *(float4*)&sx[l][di] = xv;
            sres[l][di + 0] = bf2f(rv.x);
            sres[l][di + 1] = bf2f(rv.y);
            sres[l][di + 2] = bf2f(rv.z);
            sres[l][di + 3] = bf2f(rv.w);
            const int r0 = tid >> 3, c4 = (tid & 7) << 2;
            *(float4*)&sbc[r0][c4] = *(const float4*)&bc[((size_t)(b * 1024 + l0 + r0)) * 32 + c4];
            const int r1 = (tid + 256) >> 3;
            *(float4*)&sbc[r1][c4] = *(const float4*)&bc[((size_t)(b * 1024 + l0 + r1)) * 32 + c4];
        }
        __syncthreads();

        for (int l16 = 0; l16 < 4; l16++) {
#pragma unroll
            for (int j = 0; j < 16; j++) {
                const int l = l16 * 16 + j;
                const float dtv = sdt[l][ch];
                const float a = __expf(dtv * Aln);
                h = fmaf(a, h, sdtx[l][ch] * sbc[l][n]);
                pw[j * 68 + ch4 * 16 + n] = h * sbc[l][16 + n];
            }
            __builtin_amdgcn_wave_barrier();
            const float4 q0 = *(const float4*)&pw[n * 68 + ch4 * 16 + 0];
            const float4 q1 = *(const float4*)&pw[n * 68 + ch4 * 16 + 4];
            const float4 q2 = *(const float4*)&pw[n * 68 + ch4 * 16 + 8];
            const float4 q3 = *(const float4*)&pw[n * 68 + ch4 * 16 + 12];
            const float sum = ((q0.x + q0.y) + (q0.z + q0.w)) + ((q1.x + q1.y) + (q1.z + q1.w))
                            + ((q2.x + q2.y) + (q2.z + q2.w)) + ((q3.x + q3.y) + (q3.z + q3.w));
            const int t = l16 * 16 + n;
            const float xv = sx[t][ch];
            const float rv = sres[t][ch];
            const float yv = (sum + xv * Dv) * silu_f(rv);
            ybf[((size_t)(b * 1024 + l0 + t)) * D_INNER + d] = f2bf(yv);
            __builtin_amdgcn_wave_barrier();
        }
    }
}

// ---------------------------------------------------------------------------
// LayerNorm over D_MODEL=1024 per row.
// ---------------------------------------------------------------------------
__global__ __launch_bounds__(256)
void layernorm_kernel(const float* __restrict__ z, const float* __restrict__ g,
                      const float* __restrict__ beta, float* __restrict__ out)
{
    const int row = blockIdx.x;
    const int tid = threadIdx.x;
    const float* zr = z + (size_t)row * D_MODEL;
    const float4 v = *(const float4*)&zr[tid << 2];
    float s = v.x + v.y + v.z + v.w;
    float ss = v.x * v.x + v.y * v.y + v.z * v.z + v.w * v.w;

    __shared__ float sm[256], sq[256];
    sm[tid] = s; sq[tid] = ss;
    __syncthreads();
    for (int off = 128; off > 0; off >>= 1) {
        if (tid < off) { sm[tid] += sm[tid + off]; sq[tid] += sq[tid + off]; }
        __syncthreads();
    }
    const float mean = sm[0] * (1.f / D_MODEL);
    const float var = sq[0] * (1.f / D_MODEL) - mean * mean;
    const float rstd = rsqrtf(var + 1e-5f);

    float4 o;
    o.x = (v.x - mean) * rstd * g[(tid << 2) + 0] + beta[(tid << 2) + 0];
    o.y = (v.y - mean) * rstd * g[(tid << 2) + 1] + beta[(tid << 2) + 1];
    o.z = (v.z - mean) * rstd * g[(tid << 2) + 2] + beta[(tid << 2) + 2];
    o.w = (v.w - mean) * rstd * g[(tid << 2) + 3] + beta[(tid << 2) + 3];
    *(float4*)&out[(size_t)row * D_MODEL + (tid << 2)] = o;
}

// ---------------------------------------------------------------------------
extern "C" void kernel_launch(void* const* d_in, const int* in_sizes, int n_in,
                              void* d_out, int out_size, void* d_ws, size_t ws_size,
                              hipStream_t stream)
{
    const float* x      = (const float*)d_in[0];
    const float* W_in   = (const float*)d_in[1];
    const float* b_in   = (const float*)d_in[2];
    const float* conv_w = (const float*)d_in[3];
    const float* conv_b = (const float*)d_in[4];
    const float* W_xp   = (const float*)d_in[5];
    const float* b_xp   = (const float*)d_in[6];
    const float* W_dt   = (const float*)d_in[7];
    const float* b_dt   = (const float*)d_in[8];
    const float* A_log  = (const float*)d_in[9];
    const float* D_par  = (const float*)d_in[10];
    const float* W_out  = (const float*)d_in[11];
    const float* b_out  = (const float*)d_in[12];
    const float* ln_g   = (const float*)d_in[13];
    const float* ln_b   = (const float*)d_in[14];
    float* out = (float*)d_out;

    const int BL = in_sizes[0] / D_MODEL;   // 4096
    const int Bb = BL / 1024;               // 4
    const size_t BLD = (size_t)BL * D_INNER;

    // workspace layout (floats unless noted)
    float* ws    = (float*)d_ws;
    float* xcb   = ws;                                   // BLD f32 (conv out)
    float* dtb   = xcb + BLD;                            // BLD f32 ; later zbuf
    float* bcbuf = dtb + BLD;                            // BL*32
    float* hend  = bcbuf + (size_t)BL * 32;              // Bb*8*2048*16 = 4 MB
    float* dtsum = hend + (size_t)Bb * NCHUNK * D_INNER * D_STATE;
    u16*   xibf  = (u16*)(dtsum + (size_t)Bb * NCHUNK * D_INNER);  // BLD u16 ; later ybf
    u16*   resbf = xibf + BLD;                           // BLD u16
    u16*   xcbf  = resbf + BLD;                          // BLD u16
    u16*   xbf   = xcbf + BLD;                           // BL*1024 u16
    u16*   wxpT  = xbf + (size_t)BL * D_MODEL;           // 32*2048 u16
    u16*   wtmp  = wxpT + 32 * D_INNER;                  // up to 4M u16
    u16*   ybf   = xibf;
    float* zbuf  = dtb;

    // 1) x -> bf16
    f32_to_bf16_kernel<<<(BL * D_MODEL / 4 + 255) / 256, 256, 0, stream>>>(x, xbf, BL * D_MODEL / 4);

    // 2) W_in (1024x4096) -> Wt bf16 (4096x1024)
    transpose_bf16_kernel<<<dim3(2 * D_INNER / 32, D_MODEL / 32), 256, 0, stream>>>(W_in, wtmp, D_MODEL, 2 * D_INNER);

    // 3) in_proj GEMM: silu-half (bf16) + gate-half (bf16)
    gemm_mfma<0><<<dim3(2 * D_INNER / 128, BL / 128), 256, 0, stream>>>(
        xbf, wtmp, b_in, nullptr, xibf, resbf, BL, 2 * D_INNER, D_MODEL);

    // 4) W_xp (2048x32) -> WxpT bf16 (32x2048)
    transpose_bf16_kernel<<<dim3(1, D_INNER / 32), 256, 0, stream>>>(W_xp, wxpT, D_INNER, 32);

    // 5) depthwise causal conv + silu (bf16 in; f32 + bf16 out)
    conv_silu_kernel<<<(int)(BLD / 256), 256, 0, stream>>>(
        xibf, conv_w, conv_b, xcb, xcbf, (int)BLD);

    // 6) x_proj -> B,C via MFMA (f32 out)
    xproj_mfma_kernel<<<BL / 64, 256, 0, stream>>>(xcbf, wxpT, b_xp, bcbuf);

    // 7) W_dt (2048x2048) -> Wt bf16
    transpose_bf16_kernel<<<dim3(D_INNER / 32, D_INNER / 32), 256, 0, stream>>>(W_dt, wtmp, D_INNER, D_INNER);

    // 8) dt_proj GEMM + softplus (f32 out)
    gemm_mfma<1><<<dim3(D_INNER / 128, BL / 128), 256, 0, stream>>>(
        xcbf, wtmp, b_dt, nullptr, dtb, nullptr, BL, D_INNER, D_INNER);

    // 9a) scan phase 1: chunk-local end states + dt sums
    ssm_s1_kernel<<<dim3(D_INNER / 16, NCHUNK, Bb), 256, 0, stream>>>(
        xcb, dtb, bcbuf, A_log, hend, dtsum);

    // 9b) scan phase 3: combine + rerun + emit y (bf16)
    ssm_s3_kernel<<<dim3(D_INNER / 16, NCHUNK, Bb), 256, 0, stream>>>(
        xcb, dtb, bcbuf, A_log, D_par, resbf, hend, dtsum, ybf);

    // 10) W_out (2048x1024) -> Wt bf16
    transpose_bf16_kernel<<<dim3(D_MODEL / 32, D_INNER / 32), 256, 0, stream>>>(W_out, wtmp, D_INNER, D_MODEL);

    // 11) out_proj GEMM + bias + residual (f32 out)
    gemm_mfma<2><<<dim3(D_MODEL / 128, BL / 128), 256, 0, stream>>>(
        ybf, wtmp, b_out, x, zbuf, nullptr, BL, D_MODEL, D_INNER);

    // 12) LayerNorm
    layernorm_kernel<<<BL, 256, 0, stream>>>(zbuf, ln_g, ln_b, out);
}